// Round 1
// baseline (8370.387 us; speedup 1.0000x reference)
//
#include <hip/hip_runtime.h>

#define N_NODES 50000
#define E_EDGES 800000
#define D_FEAT  96
#define C_CLS   40
#define N_ITER  8

// ---------------------------------------------------------------------------
// Kernel 1: support = h @ W_gc   (and zero agg for the coming scatter)
// Mapping: 4 threads per node, each computes 24 output columns.
// W_gc (96x96 = 36KB) staged in LDS; all lanes with the same q read the same
// float4 -> broadcast, conflict-free.
// ---------------------------------------------------------------------------
__global__ __launch_bounds__(256) void k_matmul(const float* __restrict__ h,
                                                const float* __restrict__ W,
                                                float* __restrict__ support,
                                                float* __restrict__ agg) {
    __shared__ float Wl[D_FEAT * D_FEAT];
    {
        const float4* src = (const float4*)W;
        float4* dst = (float4*)Wl;
        // 9216 floats = 2304 float4; 256 threads x 9
        #pragma unroll
        for (int i = 0; i < 9; ++i)
            dst[threadIdx.x + 256 * i] = src[threadIdx.x + 256 * i];
    }
    __syncthreads();

    int gid = blockIdx.x * 256 + threadIdx.x;
    int n = gid >> 2;
    int q = gid & 3;           // which 24-column slice
    if (n >= N_NODES) return;

    float acc[24];
    #pragma unroll
    for (int j = 0; j < 24; ++j) acc[j] = 0.0f;

    const float4* hrow = (const float4*)(h + (size_t)n * D_FEAT);
    const int cbase = q * 24;

    for (int k4 = 0; k4 < 24; ++k4) {
        float4 hv = hrow[k4];
        const float* hvf = (const float*)&hv;
        #pragma unroll
        for (int kk = 0; kk < 4; ++kk) {
            float hs = hvf[kk];
            const float* wr = &Wl[(k4 * 4 + kk) * D_FEAT + cbase];
            #pragma unroll
            for (int j4 = 0; j4 < 6; ++j4) {
                float4 w = *(const float4*)(wr + j4 * 4);
                acc[j4 * 4 + 0] = fmaf(hs, w.x, acc[j4 * 4 + 0]);
                acc[j4 * 4 + 1] = fmaf(hs, w.y, acc[j4 * 4 + 1]);
                acc[j4 * 4 + 2] = fmaf(hs, w.z, acc[j4 * 4 + 2]);
                acc[j4 * 4 + 3] = fmaf(hs, w.w, acc[j4 * 4 + 3]);
            }
        }
    }

    float* srow = support + (size_t)n * D_FEAT + cbase;
    float* arow = agg     + (size_t)n * D_FEAT + cbase;
    #pragma unroll
    for (int j4 = 0; j4 < 6; ++j4) {
        *(float4*)(srow + j4 * 4) =
            make_float4(acc[j4 * 4 + 0], acc[j4 * 4 + 1],
                        acc[j4 * 4 + 2], acc[j4 * 4 + 3]);
        *(float4*)(arow + j4 * 4) = make_float4(0.f, 0.f, 0.f, 0.f);
    }
}

// ---------------------------------------------------------------------------
// Kernel 2: edge scatter  agg[row] += support[col] * val
// One thread per (edge, 4-feature quad): 24 threads/edge. Gather is a
// coalesced-within-edge float4; 4 atomicAdds per thread. agg is 19.2MB ->
// L2/L3 resident.
// ---------------------------------------------------------------------------
__global__ __launch_bounds__(256) void k_scatter(const int* __restrict__ erow,
                                                 const int* __restrict__ ecol,
                                                 const float* __restrict__ eval_,
                                                 const float* __restrict__ support,
                                                 float* __restrict__ agg) {
    int gid = blockIdx.x * 256 + threadIdx.x;    // up to E*24 = 19.2M < 2^31
    if (gid >= E_EDGES * 24) return;
    int e = gid / 24;
    int q = gid - e * 24;
    int r = erow[e];
    int c = ecol[e];
    float v = eval_[e];
    float4 s = *(const float4*)(support + (size_t)c * D_FEAT + q * 4);
    float* a = agg + (size_t)r * D_FEAT + q * 4;
    atomicAdd(a + 0, s.x * v);
    atomicAdd(a + 1, s.y * v);
    atomicAdd(a + 2, s.z * v);
    atomicAdd(a + 3, s.w * v);
}

// ---------------------------------------------------------------------------
// Kernel 3: h = relu(0.5*hin + 0.5*(agg + b))
// ---------------------------------------------------------------------------
__global__ __launch_bounds__(256) void k_combine(const float* __restrict__ hin,
                                                 const float* __restrict__ agg,
                                                 const float* __restrict__ b,
                                                 float* __restrict__ hout) {
    int gid = blockIdx.x * 256 + threadIdx.x;   // over N*24 float4
    if (gid >= N_NODES * 24) return;
    int q = gid % 24;
    float4 hv = ((const float4*)hin)[gid];
    float4 av = ((const float4*)agg)[gid];
    float4 bv = ((const float4*)b)[q];
    float4 o;
    o.x = fmaxf(0.5f * hv.x + 0.5f * (av.x + bv.x), 0.0f);
    o.y = fmaxf(0.5f * hv.y + 0.5f * (av.y + bv.y), 0.0f);
    o.z = fmaxf(0.5f * hv.z + 0.5f * (av.z + bv.z), 0.0f);
    o.w = fmaxf(0.5f * hv.w + 0.5f * (av.w + bv.w), 0.0f);
    ((float4*)hout)[gid] = o;
}

// ---------------------------------------------------------------------------
// Kernel 4: logits = h @ W_lin ; out = log_softmax(logits)
// One thread per node, 40 accumulators; W_lin (96x40 = 15KB) in LDS,
// broadcast reads.
// ---------------------------------------------------------------------------
__global__ __launch_bounds__(256) void k_final(const float* __restrict__ h,
                                               const float* __restrict__ Wg,
                                               float* __restrict__ out) {
    __shared__ float Wl[D_FEAT * C_CLS];   // 3840 floats = 960 float4
    {
        const float4* src = (const float4*)Wg;
        float4* dst = (float4*)Wl;
        for (int i = threadIdx.x; i < 960; i += 256) dst[i] = src[i];
    }
    __syncthreads();

    int n = blockIdx.x * 256 + threadIdx.x;
    if (n >= N_NODES) return;

    float acc[C_CLS];
    #pragma unroll
    for (int c = 0; c < C_CLS; ++c) acc[c] = 0.0f;

    const float4* hrow = (const float4*)(h + (size_t)n * D_FEAT);
    for (int k4 = 0; k4 < 24; ++k4) {
        float4 hv = hrow[k4];
        const float* hvf = (const float*)&hv;
        #pragma unroll
        for (int kk = 0; kk < 4; ++kk) {
            float hs = hvf[kk];
            const float* wr = &Wl[(k4 * 4 + kk) * C_CLS];
            #pragma unroll
            for (int c4 = 0; c4 < 10; ++c4) {
                float4 w = *(const float4*)(wr + c4 * 4);
                acc[c4 * 4 + 0] = fmaf(hs, w.x, acc[c4 * 4 + 0]);
                acc[c4 * 4 + 1] = fmaf(hs, w.y, acc[c4 * 4 + 1]);
                acc[c4 * 4 + 2] = fmaf(hs, w.z, acc[c4 * 4 + 2]);
                acc[c4 * 4 + 3] = fmaf(hs, w.w, acc[c4 * 4 + 3]);
            }
        }
    }

    float m = acc[0];
    #pragma unroll
    for (int c = 1; c < C_CLS; ++c) m = fmaxf(m, acc[c]);
    float s = 0.0f;
    #pragma unroll
    for (int c = 0; c < C_CLS; ++c) s += expf(acc[c] - m);
    float lse = m + logf(s);

    float* orow = out + (size_t)n * C_CLS;   // 160B rows -> 16B aligned
    #pragma unroll
    for (int c4 = 0; c4 < 10; ++c4) {
        *(float4*)(orow + c4 * 4) =
            make_float4(acc[c4 * 4 + 0] - lse, acc[c4 * 4 + 1] - lse,
                        acc[c4 * 4 + 2] - lse, acc[c4 * 4 + 3] - lse);
    }
}

// ---------------------------------------------------------------------------
extern "C" void kernel_launch(void* const* d_in, const int* in_sizes, int n_in,
                              void* d_out, int out_size, void* d_ws, size_t ws_size,
                              hipStream_t stream) {
    const float* x    = (const float*)d_in[0];
    const int*   erow = (const int*)  d_in[1];
    const int*   ecol = (const int*)  d_in[2];
    const float* ev   = (const float*)d_in[3];
    const float* Wgc  = (const float*)d_in[4];
    const float* bgc  = (const float*)d_in[5];
    const float* Wlin = (const float*)d_in[6];
    float* out = (float*)d_out;

    const size_t NF = (size_t)N_NODES * D_FEAT;
    float* h       = (float*)d_ws;
    float* support = h + NF;
    float* agg     = support + NF;

    const int g_mm  = (N_NODES * 4 + 255) / 256;
    const int g_sc  = (E_EDGES * 24 + 255) / 256;
    const int g_cb  = (N_NODES * 24 + 255) / 256;
    const int g_fin = (N_NODES + 255) / 256;

    for (int it = 0; it < N_ITER; ++it) {
        const float* hin = (it == 0) ? x : h;
        k_matmul <<<g_mm, 256, 0, stream>>>(hin, Wgc, support, agg);
        k_scatter<<<g_sc, 256, 0, stream>>>(erow, ecol, ev, support, agg);
        k_combine<<<g_cb, 256, 0, stream>>>(hin, agg, bgc, h);
    }
    k_final<<<g_fin, 256, 0, stream>>>(h, Wlin, out);
}

// Round 2
// 909.473 us; speedup vs baseline: 9.2036x; 9.2036x over previous
//
#include <hip/hip_runtime.h>

#define N_NODES 50000
#define E_EDGES 800000
#define D_FEAT  96
#define C_CLS   40
#define N_ITER  8

// ---------------------------------------------------------------------------
// CSR build, step 1: degree histogram (int atomics, once per launch)
// ---------------------------------------------------------------------------
__global__ __launch_bounds__(256) void k_hist(const int* __restrict__ erow,
                                              int* __restrict__ deg) {
    int e = blockIdx.x * 256 + threadIdx.x;
    if (e >= E_EDGES) return;
    atomicAdd(&deg[erow[e]], 1);
}

// ---------------------------------------------------------------------------
// CSR build, step 2: single-block exclusive scan of deg -> off (and cursor)
// 1024 threads, Hillis-Steele per 1024-chunk with running carry.
// ---------------------------------------------------------------------------
__global__ __launch_bounds__(1024) void k_scan(const int* __restrict__ deg,
                                               int* __restrict__ off,
                                               int* __restrict__ cursor) {
    __shared__ int buf[1024];
    __shared__ int carry_s;
    int tid = threadIdx.x;
    if (tid == 0) carry_s = 0;
    __syncthreads();
    for (int base = 0; base < N_NODES; base += 1024) {
        int idx = base + tid;
        int v = (idx < N_NODES) ? deg[idx] : 0;
        buf[tid] = v;
        __syncthreads();
        for (int s = 1; s < 1024; s <<= 1) {
            int t = (tid >= s) ? buf[tid - s] : 0;
            __syncthreads();
            buf[tid] += t;
            __syncthreads();
        }
        int carry = carry_s;               // stable: last write was before barrier
        if (idx < N_NODES) {
            int ex = carry + buf[tid] - v; // exclusive
            off[idx] = ex;
            cursor[idx] = ex;
        }
        __syncthreads();
        if (tid == 1023) carry_s = carry + buf[1023];
        __syncthreads();
    }
    if (tid == 0) off[N_NODES] = E_EDGES;
}

// ---------------------------------------------------------------------------
// CSR build, step 3: scatter (col, val) pairs into row-bucketed order.
// ---------------------------------------------------------------------------
__global__ __launch_bounds__(256) void k_build(const int* __restrict__ erow,
                                               const int* __restrict__ ecol,
                                               const float* __restrict__ eval_,
                                               int* __restrict__ cursor,
                                               int2* __restrict__ epairs) {
    int e = blockIdx.x * 256 + threadIdx.x;
    if (e >= E_EDGES) return;
    int r = erow[e];
    int pos = atomicAdd(&cursor[r], 1);
    int2 p;
    p.x = ecol[e];
    p.y = __float_as_int(eval_[e]);
    epairs[pos] = p;
}

// ---------------------------------------------------------------------------
// Kernel 1: support = h @ W_gc
// 4 threads per node, 24 output columns each; W_gc (36KB) in LDS, broadcast.
// ---------------------------------------------------------------------------
__global__ __launch_bounds__(256) void k_matmul(const float* __restrict__ h,
                                                const float* __restrict__ W,
                                                float* __restrict__ support) {
    __shared__ float Wl[D_FEAT * D_FEAT];
    {
        const float4* src = (const float4*)W;
        float4* dst = (float4*)Wl;
        #pragma unroll
        for (int i = 0; i < 9; ++i)
            dst[threadIdx.x + 256 * i] = src[threadIdx.x + 256 * i];
    }
    __syncthreads();

    int gid = blockIdx.x * 256 + threadIdx.x;
    int n = gid >> 2;
    int q = gid & 3;
    if (n >= N_NODES) return;

    float acc[24];
    #pragma unroll
    for (int j = 0; j < 24; ++j) acc[j] = 0.0f;

    const float4* hrow = (const float4*)(h + (size_t)n * D_FEAT);
    const int cbase = q * 24;

    for (int k4 = 0; k4 < 24; ++k4) {
        float4 hv = hrow[k4];
        const float* hvf = (const float*)&hv;
        #pragma unroll
        for (int kk = 0; kk < 4; ++kk) {
            float hs = hvf[kk];
            const float* wr = &Wl[(k4 * 4 + kk) * D_FEAT + cbase];
            #pragma unroll
            for (int j4 = 0; j4 < 6; ++j4) {
                float4 w = *(const float4*)(wr + j4 * 4);
                acc[j4 * 4 + 0] = fmaf(hs, w.x, acc[j4 * 4 + 0]);
                acc[j4 * 4 + 1] = fmaf(hs, w.y, acc[j4 * 4 + 1]);
                acc[j4 * 4 + 2] = fmaf(hs, w.z, acc[j4 * 4 + 2]);
                acc[j4 * 4 + 3] = fmaf(hs, w.w, acc[j4 * 4 + 3]);
            }
        }
    }

    float* srow = support + (size_t)n * D_FEAT + cbase;
    #pragma unroll
    for (int j4 = 0; j4 < 6; ++j4)
        *(float4*)(srow + j4 * 4) =
            make_float4(acc[j4 * 4 + 0], acc[j4 * 4 + 1],
                        acc[j4 * 4 + 2], acc[j4 * 4 + 3]);
}

// ---------------------------------------------------------------------------
// Kernel 2 (fused agg+combine): for each node n,
//   agg = sum_{e in CSR[n]} support[col(e)] * val(e)
//   hout = relu(0.5*hin + 0.5*(agg + b))
// 24 threads per node (one float4 each); block 192 = 8 nodes = 3 waves.
// Gathers hit L2/L3 (support is 19.2 MB). Zero atomics, one write per elem.
// ---------------------------------------------------------------------------
__global__ __launch_bounds__(192) void k_agg(const int* __restrict__ off,
                                             const int2* __restrict__ epairs,
                                             const float* __restrict__ support,
                                             const float* __restrict__ hin,
                                             const float* __restrict__ b,
                                             float* __restrict__ hout) {
    int gid = blockIdx.x * 192 + threadIdx.x;
    int n = gid / 24;
    int q = gid % 24;
    if (n >= N_NODES) return;

    int s = off[n];
    int e = off[n + 1];

    float4 acc = make_float4(0.f, 0.f, 0.f, 0.f);
    for (int i = s; i < e; ++i) {
        int2 p = epairs[i];               // broadcast within the 24-group (L1)
        float v = __int_as_float(p.y);
        float4 sv = *(const float4*)(support + (size_t)p.x * D_FEAT + q * 4);
        acc.x = fmaf(sv.x, v, acc.x);
        acc.y = fmaf(sv.y, v, acc.y);
        acc.z = fmaf(sv.z, v, acc.z);
        acc.w = fmaf(sv.w, v, acc.w);
    }

    float4 hv = *(const float4*)(hin + (size_t)n * D_FEAT + q * 4);
    float4 bv = *(const float4*)(b + q * 4);
    float4 o;
    o.x = fmaxf(0.5f * hv.x + 0.5f * (acc.x + bv.x), 0.0f);
    o.y = fmaxf(0.5f * hv.y + 0.5f * (acc.y + bv.y), 0.0f);
    o.z = fmaxf(0.5f * hv.z + 0.5f * (acc.z + bv.z), 0.0f);
    o.w = fmaxf(0.5f * hv.w + 0.5f * (acc.w + bv.w), 0.0f);
    *(float4*)(hout + (size_t)n * D_FEAT + q * 4) = o;
}

// ---------------------------------------------------------------------------
// Kernel 3: logits = h @ W_lin ; out = log_softmax(logits)
// ---------------------------------------------------------------------------
__global__ __launch_bounds__(256) void k_final(const float* __restrict__ h,
                                               const float* __restrict__ Wg,
                                               float* __restrict__ out) {
    __shared__ float Wl[D_FEAT * C_CLS];
    {
        const float4* src = (const float4*)Wg;
        float4* dst = (float4*)Wl;
        for (int i = threadIdx.x; i < 960; i += 256) dst[i] = src[i];
    }
    __syncthreads();

    int n = blockIdx.x * 256 + threadIdx.x;
    if (n >= N_NODES) return;

    float acc[C_CLS];
    #pragma unroll
    for (int c = 0; c < C_CLS; ++c) acc[c] = 0.0f;

    const float4* hrow = (const float4*)(h + (size_t)n * D_FEAT);
    for (int k4 = 0; k4 < 24; ++k4) {
        float4 hv = hrow[k4];
        const float* hvf = (const float*)&hv;
        #pragma unroll
        for (int kk = 0; kk < 4; ++kk) {
            float hs = hvf[kk];
            const float* wr = &Wl[(k4 * 4 + kk) * C_CLS];
            #pragma unroll
            for (int c4 = 0; c4 < 10; ++c4) {
                float4 w = *(const float4*)(wr + c4 * 4);
                acc[c4 * 4 + 0] = fmaf(hs, w.x, acc[c4 * 4 + 0]);
                acc[c4 * 4 + 1] = fmaf(hs, w.y, acc[c4 * 4 + 1]);
                acc[c4 * 4 + 2] = fmaf(hs, w.z, acc[c4 * 4 + 2]);
                acc[c4 * 4 + 3] = fmaf(hs, w.w, acc[c4 * 4 + 3]);
            }
        }
    }

    float m = acc[0];
    #pragma unroll
    for (int c = 1; c < C_CLS; ++c) m = fmaxf(m, acc[c]);
    float s = 0.0f;
    #pragma unroll
    for (int c = 0; c < C_CLS; ++c) s += expf(acc[c] - m);
    float lse = m + logf(s);

    float* orow = out + (size_t)n * C_CLS;
    #pragma unroll
    for (int c4 = 0; c4 < 10; ++c4)
        *(float4*)(orow + c4 * 4) =
            make_float4(acc[c4 * 4 + 0] - lse, acc[c4 * 4 + 1] - lse,
                        acc[c4 * 4 + 2] - lse, acc[c4 * 4 + 3] - lse);
}

// ---------------------------------------------------------------------------
extern "C" void kernel_launch(void* const* d_in, const int* in_sizes, int n_in,
                              void* d_out, int out_size, void* d_ws, size_t ws_size,
                              hipStream_t stream) {
    const float* x    = (const float*)d_in[0];
    const int*   erow = (const int*)  d_in[1];
    const int*   ecol = (const int*)  d_in[2];
    const float* ev   = (const float*)d_in[3];
    const float* Wgc  = (const float*)d_in[4];
    const float* bgc  = (const float*)d_in[5];
    const float* Wlin = (const float*)d_in[6];
    float* out = (float*)d_out;

    const size_t NF = (size_t)N_NODES * D_FEAT;
    char* ws = (char*)d_ws;
    float* h        = (float*)ws;                        ws += NF * 4;          // 19.2 MB
    float* support  = (float*)ws;                        ws += NF * 4;          // 19.2 MB
    int2*  epairs   = (int2*)ws;                         ws += (size_t)E_EDGES * 8; // 6.4 MB
    int*   off      = (int*)ws;                          ws += (N_NODES + 1) * 4;
    int*   deg      = (int*)ws;                          ws += N_NODES * 4;
    int*   cursor   = (int*)ws;                          ws += N_NODES * 4;

    // ---- CSR build (once per launch; ws is re-poisoned each call) ----
    hipMemsetAsync(deg, 0, (size_t)N_NODES * 4, stream);
    k_hist <<<(E_EDGES + 255) / 256, 256, 0, stream>>>(erow, deg);
    k_scan <<<1, 1024, 0, stream>>>(deg, off, cursor);
    k_build<<<(E_EDGES + 255) / 256, 256, 0, stream>>>(erow, ecol, ev, cursor, epairs);

    // ---- 8 GCN iterations ----
    const int g_mm  = (N_NODES * 4 + 255) / 256;
    const int g_ag  = (N_NODES + 7) / 8;          // 8 nodes per 192-thread block
    for (int it = 0; it < N_ITER; ++it) {
        const float* hin = (it == 0) ? x : h;
        k_matmul<<<g_mm, 256, 0, stream>>>(hin, Wgc, support);
        k_agg   <<<g_ag, 192, 0, stream>>>(off, epairs, support, hin, bgc, h);
    }
    k_final<<<(N_NODES + 255) / 256, 256, 0, stream>>>(h, Wlin, out);
}

// Round 3
// 747.095 us; speedup vs baseline: 11.2039x; 1.2173x over previous
//
#include <hip/hip_runtime.h>

#define N_NODES 50000
#define E_EDGES 800000
#define D_FEAT  96
#define C_CLS   40
#define N_ITER  8

#define SCAN_CHUNK 1024
#define SCAN_NB ((N_NODES + SCAN_CHUNK - 1) / SCAN_CHUNK)   // 49

// ---------------------------------------------------------------------------
// CSR build, step 1: degree histogram (int atomics, once per launch)
// ---------------------------------------------------------------------------
__global__ __launch_bounds__(256) void k_hist(const int* __restrict__ erow,
                                              int* __restrict__ deg) {
    int e = blockIdx.x * 256 + threadIdx.x;
    if (e >= E_EDGES) return;
    atomicAdd(&deg[erow[e]], 1);
}

// ---------------------------------------------------------------------------
// CSR scan 1/3: per-block (1024-elem chunk) reduction -> bsum[49]
// ---------------------------------------------------------------------------
__global__ __launch_bounds__(256) void k_scan_reduce(const int* __restrict__ deg,
                                                     int* __restrict__ bsum) {
    __shared__ int sbuf[256];
    int tid = threadIdx.x;
    int base = blockIdx.x * SCAN_CHUNK + tid * 4;
    int s = 0;
    #pragma unroll
    for (int j = 0; j < 4; ++j) {
        int idx = base + j;
        if (idx < N_NODES) s += deg[idx];
    }
    sbuf[tid] = s;
    __syncthreads();
    for (int d = 128; d > 0; d >>= 1) {
        if (tid < d) sbuf[tid] += sbuf[tid + d];
        __syncthreads();
    }
    if (tid == 0) bsum[blockIdx.x] = sbuf[0];
}

// ---------------------------------------------------------------------------
// CSR scan 2/3: exclusive scan of the 49 block sums in one wave (shfl).
// ---------------------------------------------------------------------------
__global__ __launch_bounds__(64) void k_scan_tops(int* __restrict__ bsum) {
    int lane = threadIdx.x;
    int v = (lane < SCAN_NB) ? bsum[lane] : 0;
    int inc = v;
    #pragma unroll
    for (int d = 1; d < 64; d <<= 1) {
        int up = __shfl_up(inc, d, 64);
        if (lane >= d) inc += up;
    }
    if (lane < SCAN_NB) bsum[lane] = inc - v;   // exclusive
}

// ---------------------------------------------------------------------------
// CSR scan 3/3: block-local exclusive scan + block offset -> off, cursor
// ---------------------------------------------------------------------------
__global__ __launch_bounds__(256) void k_scan_add(const int* __restrict__ deg,
                                                  const int* __restrict__ bsum_ex,
                                                  int* __restrict__ off,
                                                  int* __restrict__ cursor) {
    __shared__ int sbuf[256];
    int tid = threadIdx.x;
    int base = blockIdx.x * SCAN_CHUNK + tid * 4;
    int v[4];
    int s = 0;
    #pragma unroll
    for (int j = 0; j < 4; ++j) {
        int idx = base + j;
        v[j] = (idx < N_NODES) ? deg[idx] : 0;
        s += v[j];
    }
    sbuf[tid] = s;
    __syncthreads();
    // Hillis-Steele inclusive scan over 256 thread sums
    for (int d = 1; d < 256; d <<= 1) {
        int t = (tid >= d) ? sbuf[tid - d] : 0;
        __syncthreads();
        sbuf[tid] += t;
        __syncthreads();
    }
    int ex = bsum_ex[blockIdx.x] + sbuf[tid] - s;  // exclusive base for this thread
    #pragma unroll
    for (int j = 0; j < 4; ++j) {
        int idx = base + j;
        if (idx < N_NODES) {
            off[idx] = ex;
            cursor[idx] = ex;
            ex += v[j];
        }
    }
    if (blockIdx.x == 0 && tid == 0) off[N_NODES] = E_EDGES;
}

// ---------------------------------------------------------------------------
// CSR build, step 3: scatter (col, val) pairs into row-bucketed order.
// ---------------------------------------------------------------------------
__global__ __launch_bounds__(256) void k_build(const int* __restrict__ erow,
                                               const int* __restrict__ ecol,
                                               const float* __restrict__ eval_,
                                               int* __restrict__ cursor,
                                               int2* __restrict__ epairs) {
    int e = blockIdx.x * 256 + threadIdx.x;
    if (e >= E_EDGES) return;
    int r = erow[e];
    int pos = atomicAdd(&cursor[r], 1);
    int2 p;
    p.x = ecol[e];
    p.y = __float_as_int(eval_[e]);
    epairs[pos] = p;
}

// ---------------------------------------------------------------------------
// Kernel 1: support = h @ W_gc
// 4 threads per node, 24 output columns each; W_gc (36KB) in LDS, broadcast.
// ---------------------------------------------------------------------------
__global__ __launch_bounds__(256) void k_matmul(const float* __restrict__ h,
                                                const float* __restrict__ W,
                                                float* __restrict__ support) {
    __shared__ float Wl[D_FEAT * D_FEAT];
    {
        const float4* src = (const float4*)W;
        float4* dst = (float4*)Wl;
        #pragma unroll
        for (int i = 0; i < 9; ++i)
            dst[threadIdx.x + 256 * i] = src[threadIdx.x + 256 * i];
    }
    __syncthreads();

    int gid = blockIdx.x * 256 + threadIdx.x;
    int n = gid >> 2;
    int q = gid & 3;
    if (n >= N_NODES) return;

    float acc[24];
    #pragma unroll
    for (int j = 0; j < 24; ++j) acc[j] = 0.0f;

    const float4* hrow = (const float4*)(h + (size_t)n * D_FEAT);
    const int cbase = q * 24;

    for (int k4 = 0; k4 < 24; ++k4) {
        float4 hv = hrow[k4];
        const float* hvf = (const float*)&hv;
        #pragma unroll
        for (int kk = 0; kk < 4; ++kk) {
            float hs = hvf[kk];
            const float* wr = &Wl[(k4 * 4 + kk) * D_FEAT + cbase];
            #pragma unroll
            for (int j4 = 0; j4 < 6; ++j4) {
                float4 w = *(const float4*)(wr + j4 * 4);
                acc[j4 * 4 + 0] = fmaf(hs, w.x, acc[j4 * 4 + 0]);
                acc[j4 * 4 + 1] = fmaf(hs, w.y, acc[j4 * 4 + 1]);
                acc[j4 * 4 + 2] = fmaf(hs, w.z, acc[j4 * 4 + 2]);
                acc[j4 * 4 + 3] = fmaf(hs, w.w, acc[j4 * 4 + 3]);
            }
        }
    }

    float* srow = support + (size_t)n * D_FEAT + cbase;
    #pragma unroll
    for (int j4 = 0; j4 < 6; ++j4)
        *(float4*)(srow + j4 * 4) =
            make_float4(acc[j4 * 4 + 0], acc[j4 * 4 + 1],
                        acc[j4 * 4 + 2], acc[j4 * 4 + 3]);
}

// ---------------------------------------------------------------------------
// Kernel 2 (fused agg+combine), unroll-4 for memory-level parallelism.
// 24 threads per node (one float4 each); block 192 = 8 nodes.
// ---------------------------------------------------------------------------
__global__ __launch_bounds__(192) void k_agg(const int* __restrict__ off,
                                             const int2* __restrict__ epairs,
                                             const float* __restrict__ support,
                                             const float* __restrict__ hin,
                                             const float* __restrict__ b,
                                             float* __restrict__ hout) {
    int gid = blockIdx.x * 192 + threadIdx.x;
    int n = gid / 24;
    int q = gid % 24;
    if (n >= N_NODES) return;

    int s = off[n];
    int e = off[n + 1];

    float4 acc = make_float4(0.f, 0.f, 0.f, 0.f);
    int i = s;
    for (; i + 4 <= e; i += 4) {
        int2 p0 = epairs[i + 0];
        int2 p1 = epairs[i + 1];
        int2 p2 = epairs[i + 2];
        int2 p3 = epairs[i + 3];
        float4 s0 = *(const float4*)(support + (size_t)p0.x * D_FEAT + q * 4);
        float4 s1 = *(const float4*)(support + (size_t)p1.x * D_FEAT + q * 4);
        float4 s2 = *(const float4*)(support + (size_t)p2.x * D_FEAT + q * 4);
        float4 s3 = *(const float4*)(support + (size_t)p3.x * D_FEAT + q * 4);
        float v0 = __int_as_float(p0.y), v1 = __int_as_float(p1.y);
        float v2 = __int_as_float(p2.y), v3 = __int_as_float(p3.y);
        acc.x = fmaf(s0.x, v0, acc.x); acc.y = fmaf(s0.y, v0, acc.y);
        acc.z = fmaf(s0.z, v0, acc.z); acc.w = fmaf(s0.w, v0, acc.w);
        acc.x = fmaf(s1.x, v1, acc.x); acc.y = fmaf(s1.y, v1, acc.y);
        acc.z = fmaf(s1.z, v1, acc.z); acc.w = fmaf(s1.w, v1, acc.w);
        acc.x = fmaf(s2.x, v2, acc.x); acc.y = fmaf(s2.y, v2, acc.y);
        acc.z = fmaf(s2.z, v2, acc.z); acc.w = fmaf(s2.w, v2, acc.w);
        acc.x = fmaf(s3.x, v3, acc.x); acc.y = fmaf(s3.y, v3, acc.y);
        acc.z = fmaf(s3.z, v3, acc.z); acc.w = fmaf(s3.w, v3, acc.w);
    }
    for (; i < e; ++i) {
        int2 p = epairs[i];
        float v = __int_as_float(p.y);
        float4 sv = *(const float4*)(support + (size_t)p.x * D_FEAT + q * 4);
        acc.x = fmaf(sv.x, v, acc.x);
        acc.y = fmaf(sv.y, v, acc.y);
        acc.z = fmaf(sv.z, v, acc.z);
        acc.w = fmaf(sv.w, v, acc.w);
    }

    float4 hv = *(const float4*)(hin + (size_t)n * D_FEAT + q * 4);
    float4 bv = *(const float4*)(b + q * 4);
    float4 o;
    o.x = fmaxf(0.5f * hv.x + 0.5f * (acc.x + bv.x), 0.0f);
    o.y = fmaxf(0.5f * hv.y + 0.5f * (acc.y + bv.y), 0.0f);
    o.z = fmaxf(0.5f * hv.z + 0.5f * (acc.z + bv.z), 0.0f);
    o.w = fmaxf(0.5f * hv.w + 0.5f * (acc.w + bv.w), 0.0f);
    *(float4*)(hout + (size_t)n * D_FEAT + q * 4) = o;
}

// ---------------------------------------------------------------------------
// Kernel 3: logits = h @ W_lin ; out = log_softmax(logits)
// ---------------------------------------------------------------------------
__global__ __launch_bounds__(256) void k_final(const float* __restrict__ h,
                                               const float* __restrict__ Wg,
                                               float* __restrict__ out) {
    __shared__ float Wl[D_FEAT * C_CLS];
    {
        const float4* src = (const float4*)Wg;
        float4* dst = (float4*)Wl;
        for (int i = threadIdx.x; i < 960; i += 256) dst[i] = src[i];
    }
    __syncthreads();

    int n = blockIdx.x * 256 + threadIdx.x;
    if (n >= N_NODES) return;

    float acc[C_CLS];
    #pragma unroll
    for (int c = 0; c < C_CLS; ++c) acc[c] = 0.0f;

    const float4* hrow = (const float4*)(h + (size_t)n * D_FEAT);
    for (int k4 = 0; k4 < 24; ++k4) {
        float4 hv = hrow[k4];
        const float* hvf = (const float*)&hv;
        #pragma unroll
        for (int kk = 0; kk < 4; ++kk) {
            float hs = hvf[kk];
            const float* wr = &Wl[(k4 * 4 + kk) * C_CLS];
            #pragma unroll
            for (int c4 = 0; c4 < 10; ++c4) {
                float4 w = *(const float4*)(wr + c4 * 4);
                acc[c4 * 4 + 0] = fmaf(hs, w.x, acc[c4 * 4 + 0]);
                acc[c4 * 4 + 1] = fmaf(hs, w.y, acc[c4 * 4 + 1]);
                acc[c4 * 4 + 2] = fmaf(hs, w.z, acc[c4 * 4 + 2]);
                acc[c4 * 4 + 3] = fmaf(hs, w.w, acc[c4 * 4 + 3]);
            }
        }
    }

    float m = acc[0];
    #pragma unroll
    for (int c = 1; c < C_CLS; ++c) m = fmaxf(m, acc[c]);
    float s = 0.0f;
    #pragma unroll
    for (int c = 0; c < C_CLS; ++c) s += expf(acc[c] - m);
    float lse = m + logf(s);

    float* orow = out + (size_t)n * C_CLS;
    #pragma unroll
    for (int c4 = 0; c4 < 10; ++c4)
        *(float4*)(orow + c4 * 4) =
            make_float4(acc[c4 * 4 + 0] - lse, acc[c4 * 4 + 1] - lse,
                        acc[c4 * 4 + 2] - lse, acc[c4 * 4 + 3] - lse);
}

// ---------------------------------------------------------------------------
static inline size_t align256(size_t x) { return (x + 255) & ~(size_t)255; }

extern "C" void kernel_launch(void* const* d_in, const int* in_sizes, int n_in,
                              void* d_out, int out_size, void* d_ws, size_t ws_size,
                              hipStream_t stream) {
    const float* x    = (const float*)d_in[0];
    const int*   erow = (const int*)  d_in[1];
    const int*   ecol = (const int*)  d_in[2];
    const float* ev   = (const float*)d_in[3];
    const float* Wgc  = (const float*)d_in[4];
    const float* bgc  = (const float*)d_in[5];
    const float* Wlin = (const float*)d_in[6];
    float* out = (float*)d_out;

    const size_t NF = (size_t)N_NODES * D_FEAT;
    char* ws = (char*)d_ws;
    float* h        = (float*)ws;  ws += align256(NF * 4);                 // 19.2 MB
    float* support  = (float*)ws;  ws += align256(NF * 4);                 // 19.2 MB
    int2*  epairs   = (int2*)ws;   ws += align256((size_t)E_EDGES * 8);    // 6.4 MB
    int*   off      = (int*)ws;    ws += align256((size_t)(N_NODES + 1) * 4);
    int*   deg      = (int*)ws;    ws += align256((size_t)N_NODES * 4);
    int*   cursor   = (int*)ws;    ws += align256((size_t)N_NODES * 4);
    int*   bsum     = (int*)ws;    ws += align256((size_t)SCAN_NB * 4);

    // ---- CSR build (once per launch; ws is re-poisoned each call) ----
    hipMemsetAsync(deg, 0, (size_t)N_NODES * 4, stream);
    k_hist       <<<(E_EDGES + 255) / 256, 256, 0, stream>>>(erow, deg);
    k_scan_reduce<<<SCAN_NB, 256, 0, stream>>>(deg, bsum);
    k_scan_tops  <<<1, 64, 0, stream>>>(bsum);
    k_scan_add   <<<SCAN_NB, 256, 0, stream>>>(deg, bsum, off, cursor);
    k_build      <<<(E_EDGES + 255) / 256, 256, 0, stream>>>(erow, ecol, ev, cursor, epairs);

    // ---- 8 GCN iterations ----
    const int g_mm = (N_NODES * 4 + 255) / 256;
    const int g_ag = (N_NODES + 7) / 8;           // 8 nodes per 192-thread block
    for (int it = 0; it < N_ITER; ++it) {
        const float* hin = (it == 0) ? x : h;
        k_matmul<<<g_mm, 256, 0, stream>>>(hin, Wgc, support);
        k_agg   <<<g_ag, 192, 0, stream>>>(off, epairs, support, hin, bgc, h);
    }
    k_final<<<(N_NODES + 255) / 256, 256, 0, stream>>>(h, Wlin, out);
}

// Round 4
// 627.953 us; speedup vs baseline: 13.3296x; 1.1897x over previous
//
#include <hip/hip_runtime.h>

#define N_NODES 50000
#define E_EDGES 800000
#define D_FEAT  96
#define C_CLS   40
#define N_ITER  8

#define SCAN_CHUNK 1024
#define SCAN_NB ((N_NODES + SCAN_CHUNK - 1) / SCAN_CHUNK)   // 49

// bf16 helpers (OCP bf16 = upper 16 bits of f32, RNE rounding)
static __device__ __forceinline__ unsigned short f2bf(float f) {
    unsigned u = __float_as_uint(f);
    u = (u + 0x7FFF + ((u >> 16) & 1)) >> 16;
    return (unsigned short)u;
}
static __device__ __forceinline__ float bf2f(unsigned short s) {
    return __uint_as_float(((unsigned)s) << 16);
}

// ---------------------------------------------------------------------------
// CSR build, step 1: degree histogram
// ---------------------------------------------------------------------------
__global__ __launch_bounds__(256) void k_hist(const int* __restrict__ erow,
                                              int* __restrict__ deg) {
    int e = blockIdx.x * 256 + threadIdx.x;
    if (e >= E_EDGES) return;
    atomicAdd(&deg[erow[e]], 1);
}

// ---------------------------------------------------------------------------
// CSR scan 1/3: per-chunk reduction
// ---------------------------------------------------------------------------
__global__ __launch_bounds__(256) void k_scan_reduce(const int* __restrict__ deg,
                                                     int* __restrict__ bsum) {
    __shared__ int sbuf[256];
    int tid = threadIdx.x;
    int base = blockIdx.x * SCAN_CHUNK + tid * 4;
    int s = 0;
    #pragma unroll
    for (int j = 0; j < 4; ++j) {
        int idx = base + j;
        if (idx < N_NODES) s += deg[idx];
    }
    sbuf[tid] = s;
    __syncthreads();
    for (int d = 128; d > 0; d >>= 1) {
        if (tid < d) sbuf[tid] += sbuf[tid + d];
        __syncthreads();
    }
    if (tid == 0) bsum[blockIdx.x] = sbuf[0];
}

// ---------------------------------------------------------------------------
// CSR scan 2/3: exclusive scan of 49 block sums, one wave
// ---------------------------------------------------------------------------
__global__ __launch_bounds__(64) void k_scan_tops(int* __restrict__ bsum) {
    int lane = threadIdx.x;
    int v = (lane < SCAN_NB) ? bsum[lane] : 0;
    int inc = v;
    #pragma unroll
    for (int d = 1; d < 64; d <<= 1) {
        int up = __shfl_up(inc, d, 64);
        if (lane >= d) inc += up;
    }
    if (lane < SCAN_NB) bsum[lane] = inc - v;
}

// ---------------------------------------------------------------------------
// CSR scan 3/3: block-local scan + offset
// ---------------------------------------------------------------------------
__global__ __launch_bounds__(256) void k_scan_add(const int* __restrict__ deg,
                                                  const int* __restrict__ bsum_ex,
                                                  int* __restrict__ off,
                                                  int* __restrict__ cursor) {
    __shared__ int sbuf[256];
    int tid = threadIdx.x;
    int base = blockIdx.x * SCAN_CHUNK + tid * 4;
    int v[4];
    int s = 0;
    #pragma unroll
    for (int j = 0; j < 4; ++j) {
        int idx = base + j;
        v[j] = (idx < N_NODES) ? deg[idx] : 0;
        s += v[j];
    }
    sbuf[tid] = s;
    __syncthreads();
    for (int d = 1; d < 256; d <<= 1) {
        int t = (tid >= d) ? sbuf[tid - d] : 0;
        __syncthreads();
        sbuf[tid] += t;
        __syncthreads();
    }
    int ex = bsum_ex[blockIdx.x] + sbuf[tid] - s;
    #pragma unroll
    for (int j = 0; j < 4; ++j) {
        int idx = base + j;
        if (idx < N_NODES) {
            off[idx] = ex;
            cursor[idx] = ex;
            ex += v[j];
        }
    }
    if (blockIdx.x == 0 && tid == 0) off[N_NODES] = E_EDGES;
}

// ---------------------------------------------------------------------------
// CSR build, step 3: bucket-scatter (col,val) pairs
// ---------------------------------------------------------------------------
__global__ __launch_bounds__(256) void k_build(const int* __restrict__ erow,
                                               const int* __restrict__ ecol,
                                               const float* __restrict__ eval_,
                                               int* __restrict__ cursor,
                                               int2* __restrict__ epairs) {
    int e = blockIdx.x * 256 + threadIdx.x;
    if (e >= E_EDGES) return;
    int r = erow[e];
    int pos = atomicAdd(&cursor[r], 1);
    int2 p;
    p.x = ecol[e];
    p.y = __float_as_int(eval_[e]);
    epairs[pos] = p;
}

// ---------------------------------------------------------------------------
// Kernel 1: support(bf16) = h(f32) @ W_gc(f32)
// 2 nodes per thread (halves LDS read per FMA), 4 threads per node-pair col
// split; f32 accumulate, single RNE rounding to bf16 on store.
// ---------------------------------------------------------------------------
__global__ __launch_bounds__(256) void k_matmul(const float* __restrict__ h,
                                                const float* __restrict__ W,
                                                unsigned short* __restrict__ support) {
    __shared__ float Wl[D_FEAT * D_FEAT];
    {
        const float4* src = (const float4*)W;
        float4* dst = (float4*)Wl;
        #pragma unroll
        for (int i = 0; i < 9; ++i)
            dst[threadIdx.x + 256 * i] = src[threadIdx.x + 256 * i];
    }
    __syncthreads();

    int gid = blockIdx.x * 256 + threadIdx.x;
    int p = gid >> 2;           // node pair
    int q = gid & 3;            // 24-col slice
    if (p >= N_NODES / 2) return;
    int n0 = 2 * p, n1 = 2 * p + 1;

    float acc0[24], acc1[24];
    #pragma unroll
    for (int j = 0; j < 24; ++j) { acc0[j] = 0.0f; acc1[j] = 0.0f; }

    const float4* h0 = (const float4*)(h + (size_t)n0 * D_FEAT);
    const float4* h1 = (const float4*)(h + (size_t)n1 * D_FEAT);
    const int cbase = q * 24;

    for (int k4 = 0; k4 < 24; ++k4) {
        float4 a0 = h0[k4];
        float4 a1 = h1[k4];
        const float* a0f = (const float*)&a0;
        const float* a1f = (const float*)&a1;
        #pragma unroll
        for (int kk = 0; kk < 4; ++kk) {
            float s0 = a0f[kk];
            float s1 = a1f[kk];
            const float* wr = &Wl[(k4 * 4 + kk) * D_FEAT + cbase];
            #pragma unroll
            for (int j4 = 0; j4 < 6; ++j4) {
                float4 w = *(const float4*)(wr + j4 * 4);
                acc0[j4 * 4 + 0] = fmaf(s0, w.x, acc0[j4 * 4 + 0]);
                acc0[j4 * 4 + 1] = fmaf(s0, w.y, acc0[j4 * 4 + 1]);
                acc0[j4 * 4 + 2] = fmaf(s0, w.z, acc0[j4 * 4 + 2]);
                acc0[j4 * 4 + 3] = fmaf(s0, w.w, acc0[j4 * 4 + 3]);
                acc1[j4 * 4 + 0] = fmaf(s1, w.x, acc1[j4 * 4 + 0]);
                acc1[j4 * 4 + 1] = fmaf(s1, w.y, acc1[j4 * 4 + 1]);
                acc1[j4 * 4 + 2] = fmaf(s1, w.z, acc1[j4 * 4 + 2]);
                acc1[j4 * 4 + 3] = fmaf(s1, w.w, acc1[j4 * 4 + 3]);
            }
        }
    }

    // pack 24 f32 -> 24 bf16 = 3 x uint4 per node
    #pragma unroll
    for (int node = 0; node < 2; ++node) {
        const float* acc = node ? acc1 : acc0;
        int n = node ? n1 : n0;
        unsigned short* srow = support + (size_t)n * D_FEAT + cbase;
        #pragma unroll
        for (int g = 0; g < 3; ++g) {
            uint4 pk;
            unsigned* pku = (unsigned*)&pk;
            #pragma unroll
            for (int w2 = 0; w2 < 4; ++w2) {
                unsigned lo = f2bf(acc[g * 8 + w2 * 2 + 0]);
                unsigned hi = f2bf(acc[g * 8 + w2 * 2 + 1]);
                pku[w2] = lo | (hi << 16);
            }
            *(uint4*)(srow + g * 8) = pk;
        }
    }
}

// ---------------------------------------------------------------------------
// Kernel 2 (fused agg+combine): 12 threads per node, 8 bf16 (16B) each.
//   agg = sum_e support[col(e)] * val(e);  hout = relu(0.5*hin + 0.5*(agg+b))
// ---------------------------------------------------------------------------
__global__ __launch_bounds__(192) void k_agg(const int* __restrict__ off,
                                             const int2* __restrict__ epairs,
                                             const unsigned short* __restrict__ support,
                                             const float* __restrict__ hin,
                                             const float* __restrict__ b,
                                             float* __restrict__ hout) {
    int gid = blockIdx.x * 192 + threadIdx.x;
    int n = gid / 12;
    int q = gid % 12;            // 8-elem group
    if (n >= N_NODES) return;

    int s = off[n];
    int e = off[n + 1];

    float acc[8];
    #pragma unroll
    for (int j = 0; j < 8; ++j) acc[j] = 0.0f;

    int i = s;
    for (; i + 4 <= e; i += 4) {
        int2 p0 = epairs[i + 0];
        int2 p1 = epairs[i + 1];
        int2 p2 = epairs[i + 2];
        int2 p3 = epairs[i + 3];
        uint4 r0 = *(const uint4*)(support + (size_t)p0.x * D_FEAT + q * 8);
        uint4 r1 = *(const uint4*)(support + (size_t)p1.x * D_FEAT + q * 8);
        uint4 r2 = *(const uint4*)(support + (size_t)p2.x * D_FEAT + q * 8);
        uint4 r3 = *(const uint4*)(support + (size_t)p3.x * D_FEAT + q * 8);
        float v0 = __int_as_float(p0.y), v1 = __int_as_float(p1.y);
        float v2 = __int_as_float(p2.y), v3 = __int_as_float(p3.y);
        const unsigned* u0 = (const unsigned*)&r0;
        const unsigned* u1 = (const unsigned*)&r1;
        const unsigned* u2 = (const unsigned*)&r2;
        const unsigned* u3 = (const unsigned*)&r3;
        #pragma unroll
        for (int w2 = 0; w2 < 4; ++w2) {
            acc[w2*2+0] = fmaf(__uint_as_float(u0[w2] << 16),          v0, acc[w2*2+0]);
            acc[w2*2+1] = fmaf(__uint_as_float(u0[w2] & 0xFFFF0000u),  v0, acc[w2*2+1]);
            acc[w2*2+0] = fmaf(__uint_as_float(u1[w2] << 16),          v1, acc[w2*2+0]);
            acc[w2*2+1] = fmaf(__uint_as_float(u1[w2] & 0xFFFF0000u),  v1, acc[w2*2+1]);
            acc[w2*2+0] = fmaf(__uint_as_float(u2[w2] << 16),          v2, acc[w2*2+0]);
            acc[w2*2+1] = fmaf(__uint_as_float(u2[w2] & 0xFFFF0000u),  v2, acc[w2*2+1]);
            acc[w2*2+0] = fmaf(__uint_as_float(u3[w2] << 16),          v3, acc[w2*2+0]);
            acc[w2*2+1] = fmaf(__uint_as_float(u3[w2] & 0xFFFF0000u),  v3, acc[w2*2+1]);
        }
    }
    for (; i < e; ++i) {
        int2 p = epairs[i];
        float v = __int_as_float(p.y);
        uint4 r = *(const uint4*)(support + (size_t)p.x * D_FEAT + q * 8);
        const unsigned* u = (const unsigned*)&r;
        #pragma unroll
        for (int w2 = 0; w2 < 4; ++w2) {
            acc[w2*2+0] = fmaf(__uint_as_float(u[w2] << 16),         v, acc[w2*2+0]);
            acc[w2*2+1] = fmaf(__uint_as_float(u[w2] & 0xFFFF0000u), v, acc[w2*2+1]);
        }
    }

    const float* hrow = hin + (size_t)n * D_FEAT + q * 8;
    const float* brow = b + q * 8;
    float* orow = hout + (size_t)n * D_FEAT + q * 8;
    #pragma unroll
    for (int g = 0; g < 2; ++g) {
        float4 hv = *(const float4*)(hrow + g * 4);
        float4 bv = *(const float4*)(brow + g * 4);
        float4 o;
        o.x = fmaxf(0.5f * hv.x + 0.5f * (acc[g*4+0] + bv.x), 0.0f);
        o.y = fmaxf(0.5f * hv.y + 0.5f * (acc[g*4+1] + bv.y), 0.0f);
        o.z = fmaxf(0.5f * hv.z + 0.5f * (acc[g*4+2] + bv.z), 0.0f);
        o.w = fmaxf(0.5f * hv.w + 0.5f * (acc[g*4+3] + bv.w), 0.0f);
        *(float4*)(orow + g * 4) = o;
    }
}

// ---------------------------------------------------------------------------
// Kernel 3: logits = h @ W_lin ; out = log_softmax(logits)
// ---------------------------------------------------------------------------
__global__ __launch_bounds__(256) void k_final(const float* __restrict__ h,
                                               const float* __restrict__ Wg,
                                               float* __restrict__ out) {
    __shared__ float Wl[D_FEAT * C_CLS];
    {
        const float4* src = (const float4*)Wg;
        float4* dst = (float4*)Wl;
        for (int i = threadIdx.x; i < 960; i += 256) dst[i] = src[i];
    }
    __syncthreads();

    int n = blockIdx.x * 256 + threadIdx.x;
    if (n >= N_NODES) return;

    float acc[C_CLS];
    #pragma unroll
    for (int c = 0; c < C_CLS; ++c) acc[c] = 0.0f;

    const float4* hrow = (const float4*)(h + (size_t)n * D_FEAT);
    for (int k4 = 0; k4 < 24; ++k4) {
        float4 hv = hrow[k4];
        const float* hvf = (const float*)&hv;
        #pragma unroll
        for (int kk = 0; kk < 4; ++kk) {
            float hs = hvf[kk];
            const float* wr = &Wl[(k4 * 4 + kk) * C_CLS];
            #pragma unroll
            for (int c4 = 0; c4 < 10; ++c4) {
                float4 w = *(const float4*)(wr + c4 * 4);
                acc[c4 * 4 + 0] = fmaf(hs, w.x, acc[c4 * 4 + 0]);
                acc[c4 * 4 + 1] = fmaf(hs, w.y, acc[c4 * 4 + 1]);
                acc[c4 * 4 + 2] = fmaf(hs, w.z, acc[c4 * 4 + 2]);
                acc[c4 * 4 + 3] = fmaf(hs, w.w, acc[c4 * 4 + 3]);
            }
        }
    }

    float m = acc[0];
    #pragma unroll
    for (int c = 1; c < C_CLS; ++c) m = fmaxf(m, acc[c]);
    float s = 0.0f;
    #pragma unroll
    for (int c = 0; c < C_CLS; ++c) s += expf(acc[c] - m);
    float lse = m + logf(s);

    float* orow = out + (size_t)n * C_CLS;
    #pragma unroll
    for (int c4 = 0; c4 < 10; ++c4)
        *(float4*)(orow + c4 * 4) =
            make_float4(acc[c4 * 4 + 0] - lse, acc[c4 * 4 + 1] - lse,
                        acc[c4 * 4 + 2] - lse, acc[c4 * 4 + 3] - lse);
}

// ---------------------------------------------------------------------------
static inline size_t align256(size_t x) { return (x + 255) & ~(size_t)255; }

extern "C" void kernel_launch(void* const* d_in, const int* in_sizes, int n_in,
                              void* d_out, int out_size, void* d_ws, size_t ws_size,
                              hipStream_t stream) {
    const float* x    = (const float*)d_in[0];
    const int*   erow = (const int*)  d_in[1];
    const int*   ecol = (const int*)  d_in[2];
    const float* ev   = (const float*)d_in[3];
    const float* Wgc  = (const float*)d_in[4];
    const float* bgc  = (const float*)d_in[5];
    const float* Wlin = (const float*)d_in[6];
    float* out = (float*)d_out;

    const size_t NF = (size_t)N_NODES * D_FEAT;
    char* ws = (char*)d_ws;
    float*          h          = (float*)ws;          ws += align256(NF * 4);              // 19.2 MB
    unsigned short* support_bf = (unsigned short*)ws; ws += align256(NF * 2);              // 9.6 MB
    int2*           epairs     = (int2*)ws;           ws += align256((size_t)E_EDGES * 8); // 6.4 MB
    int*            off        = (int*)ws;            ws += align256((size_t)(N_NODES + 1) * 4);
    int*            deg        = (int*)ws;            ws += align256((size_t)N_NODES * 4);
    int*            cursor     = (int*)ws;            ws += align256((size_t)N_NODES * 4);
    int*            bsum       = (int*)ws;            ws += align256((size_t)SCAN_NB * 4);

    // ---- CSR build (once per launch) ----
    hipMemsetAsync(deg, 0, (size_t)N_NODES * 4, stream);
    k_hist       <<<(E_EDGES + 255) / 256, 256, 0, stream>>>(erow, deg);
    k_scan_reduce<<<SCAN_NB, 256, 0, stream>>>(deg, bsum);
    k_scan_tops  <<<1, 64, 0, stream>>>(bsum);
    k_scan_add   <<<SCAN_NB, 256, 0, stream>>>(deg, bsum, off, cursor);
    k_build      <<<(E_EDGES + 255) / 256, 256, 0, stream>>>(erow, ecol, ev, cursor, epairs);

    // ---- 8 GCN iterations ----
    const int g_mm = ((N_NODES / 2) * 4 + 255) / 256;   // 2 nodes/thread
    const int g_ag = (N_NODES * 12 + 191) / 192;        // 12 threads/node
    for (int it = 0; it < N_ITER; ++it) {
        const float* hin = (it == 0) ? x : h;
        k_matmul<<<g_mm, 256, 0, stream>>>(hin, Wgc, support_bf);
        k_agg   <<<g_ag, 192, 0, stream>>>(off, epairs, support_bf, hin, bgc, h);
    }
    k_final<<<(N_NODES + 255) / 256, 256, 0, stream>>>(h, Wlin, out);
}

// Round 5
// 529.226 us; speedup vs baseline: 15.8163x; 1.1865x over previous
//
#include <hip/hip_runtime.h>

#define N_NODES 50000
#define E_EDGES 800000
#define D_FEAT  96
#define C_CLS   40
#define N_ITER  8

#define SCAN_CHUNK 1024
#define SCAN_NB ((N_NODES + SCAN_CHUNK - 1) / SCAN_CHUNK)   // 49

typedef short bf16x8 __attribute__((ext_vector_type(8)));   // 8 bf16 = 4 VGPRs
typedef float f32x4  __attribute__((ext_vector_type(4)));

// bf16 helpers (RNE)
static __device__ __forceinline__ unsigned short f2bf(float f) {
    unsigned u = __float_as_uint(f);
    u = (u + 0x7FFF + ((u >> 16) & 1)) >> 16;
    return (unsigned short)u;
}

// ---------------------------------------------------------------------------
// CSR build, step 1: degree histogram
// ---------------------------------------------------------------------------
__global__ __launch_bounds__(256) void k_hist(const int* __restrict__ erow,
                                              int* __restrict__ deg) {
    int e = blockIdx.x * 256 + threadIdx.x;
    if (e >= E_EDGES) return;
    atomicAdd(&deg[erow[e]], 1);
}

// ---------------------------------------------------------------------------
// CSR scan 1/3: per-chunk reduction
// ---------------------------------------------------------------------------
__global__ __launch_bounds__(256) void k_scan_reduce(const int* __restrict__ deg,
                                                     int* __restrict__ bsum) {
    __shared__ int sbuf[256];
    int tid = threadIdx.x;
    int base = blockIdx.x * SCAN_CHUNK + tid * 4;
    int s = 0;
    #pragma unroll
    for (int j = 0; j < 4; ++j) {
        int idx = base + j;
        if (idx < N_NODES) s += deg[idx];
    }
    sbuf[tid] = s;
    __syncthreads();
    for (int d = 128; d > 0; d >>= 1) {
        if (tid < d) sbuf[tid] += sbuf[tid + d];
        __syncthreads();
    }
    if (tid == 0) bsum[blockIdx.x] = sbuf[0];
}

// ---------------------------------------------------------------------------
// CSR scan 2/3: exclusive scan of 49 block sums, one wave
// ---------------------------------------------------------------------------
__global__ __launch_bounds__(64) void k_scan_tops(int* __restrict__ bsum) {
    int lane = threadIdx.x;
    int v = (lane < SCAN_NB) ? bsum[lane] : 0;
    int inc = v;
    #pragma unroll
    for (int d = 1; d < 64; d <<= 1) {
        int up = __shfl_up(inc, d, 64);
        if (lane >= d) inc += up;
    }
    if (lane < SCAN_NB) bsum[lane] = inc - v;
}

// ---------------------------------------------------------------------------
// CSR scan 3/3: block-local scan + offset
// ---------------------------------------------------------------------------
__global__ __launch_bounds__(256) void k_scan_add(const int* __restrict__ deg,
                                                  const int* __restrict__ bsum_ex,
                                                  int* __restrict__ off,
                                                  int* __restrict__ cursor) {
    __shared__ int sbuf[256];
    int tid = threadIdx.x;
    int base = blockIdx.x * SCAN_CHUNK + tid * 4;
    int v[4];
    int s = 0;
    #pragma unroll
    for (int j = 0; j < 4; ++j) {
        int idx = base + j;
        v[j] = (idx < N_NODES) ? deg[idx] : 0;
        s += v[j];
    }
    sbuf[tid] = s;
    __syncthreads();
    for (int d = 1; d < 256; d <<= 1) {
        int t = (tid >= d) ? sbuf[tid - d] : 0;
        __syncthreads();
        sbuf[tid] += t;
        __syncthreads();
    }
    int ex = bsum_ex[blockIdx.x] + sbuf[tid] - s;
    #pragma unroll
    for (int j = 0; j < 4; ++j) {
        int idx = base + j;
        if (idx < N_NODES) {
            off[idx] = ex;
            cursor[idx] = ex;
            ex += v[j];
        }
    }
    if (blockIdx.x == 0 && tid == 0) off[N_NODES] = E_EDGES;
}

// ---------------------------------------------------------------------------
// CSR build, step 3: bucket-scatter (col,val) pairs
// ---------------------------------------------------------------------------
__global__ __launch_bounds__(256) void k_build(const int* __restrict__ erow,
                                               const int* __restrict__ ecol,
                                               const float* __restrict__ eval_,
                                               int* __restrict__ cursor,
                                               int2* __restrict__ epairs) {
    int e = blockIdx.x * 256 + threadIdx.x;
    if (e >= E_EDGES) return;
    int r = erow[e];
    int pos = atomicAdd(&cursor[r], 1);
    int2 p;
    p.x = ecol[e];
    p.y = __float_as_int(eval_[e]);
    epairs[pos] = p;
}

// ---------------------------------------------------------------------------
// One-time: repack W_gc (96x96 f32 row-major W[k][n]) into MFMA B-fragment
// order, bf16. Slot (t,s,lane)[j] = W[s*32+(lane>>4)*8+j][t*16+(lane&15)].
// 18 groups x 64 lanes x 8 bf16 = 18 KB.
// ---------------------------------------------------------------------------
__global__ __launch_bounds__(256) void k_prep_w(const float* __restrict__ W,
                                                unsigned short* __restrict__ WB) {
    for (int idx = threadIdx.x; idx < 18 * 64; idx += 256) {
        int grp = idx >> 6;
        int lane = idx & 63;
        int t = grp / 3, s = grp - t * 3;
        int n = t * 16 + (lane & 15);
        int k0 = s * 32 + (lane >> 4) * 8;
        unsigned short* dst = WB + (size_t)idx * 8;
        #pragma unroll
        for (int j = 0; j < 8; ++j)
            dst[j] = f2bf(W[(k0 + j) * D_FEAT + n]);
    }
}

// ---------------------------------------------------------------------------
// One-time: f32 -> bf16 row conversion (for x at iteration 0)
// ---------------------------------------------------------------------------
__global__ __launch_bounds__(256) void k_cvt_bf16(const float* __restrict__ src,
                                                  unsigned short* __restrict__ dst,
                                                  int n8) {
    int g = blockIdx.x * 256 + threadIdx.x;
    if (g >= n8) return;
    const float4* s4 = (const float4*)src + (size_t)g * 2;
    float4 x0 = s4[0], x1 = s4[1];
    const float* xf = (const float*)&x0;   // x0,x1 contiguous on stack
    float vals[8] = {x0.x, x0.y, x0.z, x0.w, x1.x, x1.y, x1.z, x1.w};
    (void)xf;
    uint4 pk; unsigned* pku = (unsigned*)&pk;
    #pragma unroll
    for (int w2 = 0; w2 < 4; ++w2) {
        unsigned lo = f2bf(vals[w2 * 2 + 0]);
        unsigned hi = f2bf(vals[w2 * 2 + 1]);
        pku[w2] = lo | (hi << 16);
    }
    *(uint4*)(dst + (size_t)g * 8) = pk;
}

// ---------------------------------------------------------------------------
// Kernel 1: support(bf16) = hb(bf16) @ WB(bf16)  via MFMA 16x16x32.
// 4 waves/block, 16 rows each (64 rows/block). K=96 = 3 MFMA steps; 6 col
// tiles. C-layout (col=lane&15,row=quad*4+reg) -> LDS stride-100 staging
// (2-way banks = free) -> coalesced uint4 bf16 stores.
// ---------------------------------------------------------------------------
__global__ __launch_bounds__(256) void k_matmul_mfma(
        const unsigned short* __restrict__ hb,
        const unsigned short* __restrict__ WB,
        unsigned short* __restrict__ support) {
    __shared__ float sm[64 * 100];
    int tid = threadIdx.x;
    int wave = tid >> 6, lane = tid & 63;
    int q = lane >> 4, c = lane & 15;
    int m0 = blockIdx.x * 64 + wave * 16;

    if (m0 < N_NODES) {
        const unsigned short* arow = hb + (size_t)(m0 + c) * D_FEAT + q * 8;
        bf16x8 a0 = *(const bf16x8*)(arow);
        bf16x8 a1 = *(const bf16x8*)(arow + 32);
        bf16x8 a2 = *(const bf16x8*)(arow + 64);
        #pragma unroll
        for (int t = 0; t < 6; ++t) {
            const unsigned short* bp = WB + ((size_t)(t * 3) * 64 + lane) * 8;
            bf16x8 b0 = *(const bf16x8*)(bp);
            bf16x8 b1 = *(const bf16x8*)(bp + 64 * 8);
            bf16x8 b2 = *(const bf16x8*)(bp + 128 * 8);
            f32x4 acc = {0.f, 0.f, 0.f, 0.f};
            acc = __builtin_amdgcn_mfma_f32_16x16x32_bf16(a0, b0, acc, 0, 0, 0);
            acc = __builtin_amdgcn_mfma_f32_16x16x32_bf16(a1, b1, acc, 0, 0, 0);
            acc = __builtin_amdgcn_mfma_f32_16x16x32_bf16(a2, b2, acc, 0, 0, 0);
            #pragma unroll
            for (int r = 0; r < 4; ++r)
                sm[(wave * 16 + q * 4 + r) * 100 + t * 16 + c] = acc[r];
        }
    }
    __syncthreads();

    // readback: 64 rows x 96 cols -> 768 uint4 outputs, 3 per thread
    #pragma unroll
    for (int oo = 0; oo < 3; ++oo) {
        int o = tid + oo * 256;
        int row = o / 12;
        int cb = (o - row * 12) * 8;
        int grow = blockIdx.x * 64 + row;
        if (grow < N_NODES) {
            const float* sp = sm + row * 100 + cb;
            uint4 pk; unsigned* pku = (unsigned*)&pk;
            #pragma unroll
            for (int w2 = 0; w2 < 4; ++w2) {
                unsigned lo = f2bf(sp[w2 * 2 + 0]);
                unsigned hi = f2bf(sp[w2 * 2 + 1]);
                pku[w2] = lo | (hi << 16);
            }
            *(uint4*)(support + (size_t)grow * D_FEAT + cb) = pk;
        }
    }
}

// ---------------------------------------------------------------------------
// Kernel 2 (fused agg+combine): 12 threads/node, 8 bf16 (16B) each.
// Writes h (f32, for skip+final) AND hb (bf16, next matmul's A input).
// ---------------------------------------------------------------------------
__global__ __launch_bounds__(192) void k_agg(const int* __restrict__ off,
                                             const int2* __restrict__ epairs,
                                             const unsigned short* __restrict__ support,
                                             const float* __restrict__ hin,
                                             const float* __restrict__ b,
                                             float* __restrict__ hout,
                                             unsigned short* __restrict__ hb) {
    int gid = blockIdx.x * 192 + threadIdx.x;
    int n = gid / 12;
    int q = gid % 12;
    if (n >= N_NODES) return;

    int s = off[n];
    int e = off[n + 1];

    float acc[8];
    #pragma unroll
    for (int j = 0; j < 8; ++j) acc[j] = 0.0f;

    int i = s;
    for (; i + 4 <= e; i += 4) {
        int2 p0 = epairs[i + 0];
        int2 p1 = epairs[i + 1];
        int2 p2 = epairs[i + 2];
        int2 p3 = epairs[i + 3];
        uint4 r0 = *(const uint4*)(support + (size_t)p0.x * D_FEAT + q * 8);
        uint4 r1 = *(const uint4*)(support + (size_t)p1.x * D_FEAT + q * 8);
        uint4 r2 = *(const uint4*)(support + (size_t)p2.x * D_FEAT + q * 8);
        uint4 r3 = *(const uint4*)(support + (size_t)p3.x * D_FEAT + q * 8);
        float v0 = __int_as_float(p0.y), v1 = __int_as_float(p1.y);
        float v2 = __int_as_float(p2.y), v3 = __int_as_float(p3.y);
        const unsigned* u0 = (const unsigned*)&r0;
        const unsigned* u1 = (const unsigned*)&r1;
        const unsigned* u2 = (const unsigned*)&r2;
        const unsigned* u3 = (const unsigned*)&r3;
        #pragma unroll
        for (int w2 = 0; w2 < 4; ++w2) {
            acc[w2*2+0] = fmaf(__uint_as_float(u0[w2] << 16),          v0, acc[w2*2+0]);
            acc[w2*2+1] = fmaf(__uint_as_float(u0[w2] & 0xFFFF0000u),  v0, acc[w2*2+1]);
            acc[w2*2+0] = fmaf(__uint_as_float(u1[w2] << 16),          v1, acc[w2*2+0]);
            acc[w2*2+1] = fmaf(__uint_as_float(u1[w2] & 0xFFFF0000u),  v1, acc[w2*2+1]);
            acc[w2*2+0] = fmaf(__uint_as_float(u2[w2] << 16),          v2, acc[w2*2+0]);
            acc[w2*2+1] = fmaf(__uint_as_float(u2[w2] & 0xFFFF0000u),  v2, acc[w2*2+1]);
            acc[w2*2+0] = fmaf(__uint_as_float(u3[w2] << 16),          v3, acc[w2*2+0]);
            acc[w2*2+1] = fmaf(__uint_as_float(u3[w2] & 0xFFFF0000u),  v3, acc[w2*2+1]);
        }
    }
    for (; i < e; ++i) {
        int2 p = epairs[i];
        float v = __int_as_float(p.y);
        uint4 r = *(const uint4*)(support + (size_t)p.x * D_FEAT + q * 8);
        const unsigned* u = (const unsigned*)&r;
        #pragma unroll
        for (int w2 = 0; w2 < 4; ++w2) {
            acc[w2*2+0] = fmaf(__uint_as_float(u[w2] << 16),         v, acc[w2*2+0]);
            acc[w2*2+1] = fmaf(__uint_as_float(u[w2] & 0xFFFF0000u), v, acc[w2*2+1]);
        }
    }

    const float* hrow = hin + (size_t)n * D_FEAT + q * 8;
    const float* brow = b + q * 8;
    float* orow = hout + (size_t)n * D_FEAT + q * 8;
    float og[8];
    #pragma unroll
    for (int g = 0; g < 2; ++g) {
        float4 hv = *(const float4*)(hrow + g * 4);
        float4 bv = *(const float4*)(brow + g * 4);
        float4 o;
        o.x = fmaxf(0.5f * hv.x + 0.5f * (acc[g*4+0] + bv.x), 0.0f);
        o.y = fmaxf(0.5f * hv.y + 0.5f * (acc[g*4+1] + bv.y), 0.0f);
        o.z = fmaxf(0.5f * hv.z + 0.5f * (acc[g*4+2] + bv.z), 0.0f);
        o.w = fmaxf(0.5f * hv.w + 0.5f * (acc[g*4+3] + bv.w), 0.0f);
        *(float4*)(orow + g * 4) = o;
        og[g*4+0] = o.x; og[g*4+1] = o.y; og[g*4+2] = o.z; og[g*4+3] = o.w;
    }
    uint4 pk; unsigned* pku = (unsigned*)&pk;
    #pragma unroll
    for (int w2 = 0; w2 < 4; ++w2) {
        unsigned lo = f2bf(og[w2 * 2 + 0]);
        unsigned hi = f2bf(og[w2 * 2 + 1]);
        pku[w2] = lo | (hi << 16);
    }
    *(uint4*)(hb + (size_t)n * D_FEAT + q * 8) = pk;
}

// ---------------------------------------------------------------------------
// Kernel 3: logits = h @ W_lin ; out = log_softmax(logits)  (f32 throughout)
// ---------------------------------------------------------------------------
__global__ __launch_bounds__(256) void k_final(const float* __restrict__ h,
                                               const float* __restrict__ Wg,
                                               float* __restrict__ out) {
    __shared__ float Wl[D_FEAT * C_CLS];
    {
        const float4* src = (const float4*)Wg;
        float4* dst = (float4*)Wl;
        for (int i = threadIdx.x; i < 960; i += 256) dst[i] = src[i];
    }
    __syncthreads();

    int n = blockIdx.x * 256 + threadIdx.x;
    if (n >= N_NODES) return;

    float acc[C_CLS];
    #pragma unroll
    for (int c = 0; c < C_CLS; ++c) acc[c] = 0.0f;

    const float4* hrow = (const float4*)(h + (size_t)n * D_FEAT);
    for (int k4 = 0; k4 < 24; ++k4) {
        float4 hv = hrow[k4];
        const float* hvf = (const float*)&hv;
        #pragma unroll
        for (int kk = 0; kk < 4; ++kk) {
            float hs = hvf[kk];
            const float* wr = &Wl[(k4 * 4 + kk) * C_CLS];
            #pragma unroll
            for (int c4 = 0; c4 < 10; ++c4) {
                float4 w = *(const float4*)(wr + c4 * 4);
                acc[c4 * 4 + 0] = fmaf(hs, w.x, acc[c4 * 4 + 0]);
                acc[c4 * 4 + 1] = fmaf(hs, w.y, acc[c4 * 4 + 1]);
                acc[c4 * 4 + 2] = fmaf(hs, w.z, acc[c4 * 4 + 2]);
                acc[c4 * 4 + 3] = fmaf(hs, w.w, acc[c4 * 4 + 3]);
            }
        }
    }

    float m = acc[0];
    #pragma unroll
    for (int c = 1; c < C_CLS; ++c) m = fmaxf(m, acc[c]);
    float s = 0.0f;
    #pragma unroll
    for (int c = 0; c < C_CLS; ++c) s += expf(acc[c] - m);
    float lse = m + logf(s);

    float* orow = out + (size_t)n * C_CLS;
    #pragma unroll
    for (int c4 = 0; c4 < 10; ++c4)
        *(float4*)(orow + c4 * 4) =
            make_float4(acc[c4 * 4 + 0] - lse, acc[c4 * 4 + 1] - lse,
                        acc[c4 * 4 + 2] - lse, acc[c4 * 4 + 3] - lse);
}

// ---------------------------------------------------------------------------
static inline size_t align256(size_t x) { return (x + 255) & ~(size_t)255; }

extern "C" void kernel_launch(void* const* d_in, const int* in_sizes, int n_in,
                              void* d_out, int out_size, void* d_ws, size_t ws_size,
                              hipStream_t stream) {
    const float* x    = (const float*)d_in[0];
    const int*   erow = (const int*)  d_in[1];
    const int*   ecol = (const int*)  d_in[2];
    const float* ev   = (const float*)d_in[3];
    const float* Wgc  = (const float*)d_in[4];
    const float* bgc  = (const float*)d_in[5];
    const float* Wlin = (const float*)d_in[6];
    float* out = (float*)d_out;

    const size_t NF = (size_t)N_NODES * D_FEAT;
    char* ws = (char*)d_ws;
    float*          h          = (float*)ws;          ws += align256(NF * 4);              // 19.2 MB
    unsigned short* support_bf = (unsigned short*)ws; ws += align256(NF * 2);              // 9.6 MB
    unsigned short* hb         = (unsigned short*)ws; ws += align256(NF * 2);              // 9.6 MB
    unsigned short* xb         = (unsigned short*)ws; ws += align256(NF * 2);              // 9.6 MB
    int2*           epairs     = (int2*)ws;           ws += align256((size_t)E_EDGES * 8); // 6.4 MB
    unsigned short* WB         = (unsigned short*)ws; ws += align256((size_t)18 * 64 * 8 * 2);
    int*            off        = (int*)ws;            ws += align256((size_t)(N_NODES + 1) * 4);
    int*            deg        = (int*)ws;            ws += align256((size_t)N_NODES * 4);
    int*            cursor     = (int*)ws;            ws += align256((size_t)N_NODES * 4);
    int*            bsum       = (int*)ws;            ws += align256((size_t)SCAN_NB * 4);

    // ---- one-time prep + CSR build ----
    hipMemsetAsync(deg, 0, (size_t)N_NODES * 4, stream);
    k_prep_w     <<<1, 256, 0, stream>>>(Wgc, WB);
    k_cvt_bf16   <<<(int)((NF / 8 + 255) / 256), 256, 0, stream>>>(x, xb, (int)(NF / 8));
    k_hist       <<<(E_EDGES + 255) / 256, 256, 0, stream>>>(erow, deg);
    k_scan_reduce<<<SCAN_NB, 256, 0, stream>>>(deg, bsum);
    k_scan_tops  <<<1, 64, 0, stream>>>(bsum);
    k_scan_add   <<<SCAN_NB, 256, 0, stream>>>(deg, bsum, off, cursor);
    k_build      <<<(E_EDGES + 255) / 256, 256, 0, stream>>>(erow, ecol, ev, cursor, epairs);

    // ---- 8 GCN iterations ----
    const int g_mm = (N_NODES + 63) / 64;          // 64 rows per 256-thread block
    const int g_ag = (N_NODES * 12 + 191) / 192;   // 12 threads/node
    for (int it = 0; it < N_ITER; ++it) {
        const unsigned short* hin_bf = (it == 0) ? xb : hb;
        const float*          hin    = (it == 0) ? x  : h;
        k_matmul_mfma<<<g_mm, 256, 0, stream>>>(hin_bf, WB, support_bf);
        k_agg        <<<g_ag, 192, 0, stream>>>(off, epairs, support_bf, hin, bgc, h, hb);
    }
    k_final<<<(N_NODES + 255) / 256, 256, 0, stream>>>(h, Wlin, out);
}

// Round 6
// 528.700 us; speedup vs baseline: 15.8320x; 1.0010x over previous
//
#include <hip/hip_runtime.h>

#define N_NODES 50000
#define E_EDGES 800000
#define D_FEAT  96
#define C_CLS   40
#define N_ITER  8

#define SCAN_CHUNK 1024
#define SCAN_NB ((N_NODES + SCAN_CHUNK - 1) / SCAN_CHUNK)   // 49

typedef short bf16x8 __attribute__((ext_vector_type(8)));   // 8 bf16 = 4 VGPRs
typedef float f32x4  __attribute__((ext_vector_type(4)));

// bf16 helpers (RNE)
static __device__ __forceinline__ unsigned short f2bf(float f) {
    unsigned u = __float_as_uint(f);
    u = (u + 0x7FFF + ((u >> 16) & 1)) >> 16;
    return (unsigned short)u;
}

// ---------------------------------------------------------------------------
// CSR build, step 1: degree histogram
// ---------------------------------------------------------------------------
__global__ __launch_bounds__(256) void k_hist(const int* __restrict__ erow,
                                              int* __restrict__ deg) {
    int e = blockIdx.x * 256 + threadIdx.x;
    if (e >= E_EDGES) return;
    atomicAdd(&deg[erow[e]], 1);
}

// ---------------------------------------------------------------------------
// CSR scan 1/3: per-chunk reduction
// ---------------------------------------------------------------------------
__global__ __launch_bounds__(256) void k_scan_reduce(const int* __restrict__ deg,
                                                     int* __restrict__ bsum) {
    __shared__ int sbuf[256];
    int tid = threadIdx.x;
    int base = blockIdx.x * SCAN_CHUNK + tid * 4;
    int s = 0;
    #pragma unroll
    for (int j = 0; j < 4; ++j) {
        int idx = base + j;
        if (idx < N_NODES) s += deg[idx];
    }
    sbuf[tid] = s;
    __syncthreads();
    for (int d = 128; d > 0; d >>= 1) {
        if (tid < d) sbuf[tid] += sbuf[tid + d];
        __syncthreads();
    }
    if (tid == 0) bsum[blockIdx.x] = sbuf[0];
}

// ---------------------------------------------------------------------------
// CSR scan 2/3: exclusive scan of 49 block sums, one wave
// ---------------------------------------------------------------------------
__global__ __launch_bounds__(64) void k_scan_tops(int* __restrict__ bsum) {
    int lane = threadIdx.x;
    int v = (lane < SCAN_NB) ? bsum[lane] : 0;
    int inc = v;
    #pragma unroll
    for (int d = 1; d < 64; d <<= 1) {
        int up = __shfl_up(inc, d, 64);
        if (lane >= d) inc += up;
    }
    if (lane < SCAN_NB) bsum[lane] = inc - v;
}

// ---------------------------------------------------------------------------
// CSR scan 3/3: block-local scan + offset
// ---------------------------------------------------------------------------
__global__ __launch_bounds__(256) void k_scan_add(const int* __restrict__ deg,
                                                  const int* __restrict__ bsum_ex,
                                                  int* __restrict__ off,
                                                  int* __restrict__ cursor) {
    __shared__ int sbuf[256];
    int tid = threadIdx.x;
    int base = blockIdx.x * SCAN_CHUNK + tid * 4;
    int v[4];
    int s = 0;
    #pragma unroll
    for (int j = 0; j < 4; ++j) {
        int idx = base + j;
        v[j] = (idx < N_NODES) ? deg[idx] : 0;
        s += v[j];
    }
    sbuf[tid] = s;
    __syncthreads();
    for (int d = 1; d < 256; d <<= 1) {
        int t = (tid >= d) ? sbuf[tid - d] : 0;
        __syncthreads();
        sbuf[tid] += t;
        __syncthreads();
    }
    int ex = bsum_ex[blockIdx.x] + sbuf[tid] - s;
    #pragma unroll
    for (int j = 0; j < 4; ++j) {
        int idx = base + j;
        if (idx < N_NODES) {
            off[idx] = ex;
            cursor[idx] = ex;
            ex += v[j];
        }
    }
    if (blockIdx.x == 0 && tid == 0) off[N_NODES] = E_EDGES;
}

// ---------------------------------------------------------------------------
// CSR build, step 3: bucket-scatter packed edges.
// 4 B/edge: low 16 = col (50000 < 2^16), high 16 = bf16(val) so the float
// is recovered with a single AND.
// ---------------------------------------------------------------------------
__global__ __launch_bounds__(256) void k_build(const int* __restrict__ erow,
                                               const int* __restrict__ ecol,
                                               const float* __restrict__ eval_,
                                               int* __restrict__ cursor,
                                               unsigned* __restrict__ epk) {
    int e = blockIdx.x * 256 + threadIdx.x;
    if (e >= E_EDGES) return;
    int r = erow[e];
    int pos = atomicAdd(&cursor[r], 1);
    unsigned pk = (unsigned)(ecol[e] & 0xFFFF) | ((unsigned)f2bf(eval_[e]) << 16);
    epk[pos] = pk;
}

// ---------------------------------------------------------------------------
// One-time: repack W_gc into MFMA B-fragment order, bf16.
// ---------------------------------------------------------------------------
__global__ __launch_bounds__(256) void k_prep_w(const float* __restrict__ W,
                                                unsigned short* __restrict__ WB) {
    for (int idx = threadIdx.x; idx < 18 * 64; idx += 256) {
        int grp = idx >> 6;
        int lane = idx & 63;
        int t = grp / 3, s = grp - t * 3;
        int n = t * 16 + (lane & 15);
        int k0 = s * 32 + (lane >> 4) * 8;
        unsigned short* dst = WB + (size_t)idx * 8;
        #pragma unroll
        for (int j = 0; j < 8; ++j)
            dst[j] = f2bf(W[(k0 + j) * D_FEAT + n]);
    }
}

// ---------------------------------------------------------------------------
// One-time: f32 -> bf16 row conversion (x at iteration 0)
// ---------------------------------------------------------------------------
__global__ __launch_bounds__(256) void k_cvt_bf16(const float* __restrict__ src,
                                                  unsigned short* __restrict__ dst,
                                                  int n8) {
    int g = blockIdx.x * 256 + threadIdx.x;
    if (g >= n8) return;
    const float4* s4 = (const float4*)src + (size_t)g * 2;
    float4 x0 = s4[0], x1 = s4[1];
    float vals[8] = {x0.x, x0.y, x0.z, x0.w, x1.x, x1.y, x1.z, x1.w};
    uint4 pk; unsigned* pku = (unsigned*)&pk;
    #pragma unroll
    for (int w2 = 0; w2 < 4; ++w2) {
        unsigned lo = f2bf(vals[w2 * 2 + 0]);
        unsigned hi = f2bf(vals[w2 * 2 + 1]);
        pku[w2] = lo | (hi << 16);
    }
    *(uint4*)(dst + (size_t)g * 8) = pk;
}

// ---------------------------------------------------------------------------
// Kernel 1: support(bf16) = hb(bf16) @ WB(bf16) via MFMA 16x16x32.
// ---------------------------------------------------------------------------
__global__ __launch_bounds__(256) void k_matmul_mfma(
        const unsigned short* __restrict__ hb,
        const unsigned short* __restrict__ WB,
        unsigned short* __restrict__ support) {
    __shared__ float sm[64 * 100];
    int tid = threadIdx.x;
    int wave = tid >> 6, lane = tid & 63;
    int q = lane >> 4, c = lane & 15;
    int m0 = blockIdx.x * 64 + wave * 16;

    if (m0 < N_NODES) {
        const unsigned short* arow = hb + (size_t)(m0 + c) * D_FEAT + q * 8;
        bf16x8 a0 = *(const bf16x8*)(arow);
        bf16x8 a1 = *(const bf16x8*)(arow + 32);
        bf16x8 a2 = *(const bf16x8*)(arow + 64);
        #pragma unroll
        for (int t = 0; t < 6; ++t) {
            const unsigned short* bp = WB + ((size_t)(t * 3) * 64 + lane) * 8;
            bf16x8 b0 = *(const bf16x8*)(bp);
            bf16x8 b1 = *(const bf16x8*)(bp + 64 * 8);
            bf16x8 b2 = *(const bf16x8*)(bp + 128 * 8);
            f32x4 acc = {0.f, 0.f, 0.f, 0.f};
            acc = __builtin_amdgcn_mfma_f32_16x16x32_bf16(a0, b0, acc, 0, 0, 0);
            acc = __builtin_amdgcn_mfma_f32_16x16x32_bf16(a1, b1, acc, 0, 0, 0);
            acc = __builtin_amdgcn_mfma_f32_16x16x32_bf16(a2, b2, acc, 0, 0, 0);
            #pragma unroll
            for (int r = 0; r < 4; ++r)
                sm[(wave * 16 + q * 4 + r) * 100 + t * 16 + c] = acc[r];
        }
    }
    __syncthreads();

    #pragma unroll
    for (int oo = 0; oo < 3; ++oo) {
        int o = tid + oo * 256;
        int row = o / 12;
        int cb = (o - row * 12) * 8;
        int grow = blockIdx.x * 64 + row;
        if (grow < N_NODES) {
            const float* sp = sm + row * 100 + cb;
            uint4 pk; unsigned* pku = (unsigned*)&pk;
            #pragma unroll
            for (int w2 = 0; w2 < 4; ++w2) {
                unsigned lo = f2bf(sp[w2 * 2 + 0]);
                unsigned hi = f2bf(sp[w2 * 2 + 1]);
                pku[w2] = lo | (hi << 16);
            }
            *(uint4*)(support + (size_t)grow * D_FEAT + cb) = pk;
        }
    }
}

// ---------------------------------------------------------------------------
// Kernel 2 (fused agg+combine): 12 threads/node, 8 bf16 (16B) each.
// Packed 4B edges, 4 edges per uint4 load (aligned main loop).
// Writes h (f32) and hb (bf16 mirror for next matmul's A).
// ---------------------------------------------------------------------------
__global__ __launch_bounds__(192) void k_agg(const int* __restrict__ off,
                                             const unsigned* __restrict__ epk,
                                             const unsigned short* __restrict__ support,
                                             const float* __restrict__ hin,
                                             const float* __restrict__ b,
                                             float* __restrict__ hout,
                                             unsigned short* __restrict__ hb) {
    int gid = blockIdx.x * 192 + threadIdx.x;
    int n = gid / 12;
    int q = gid % 12;
    if (n >= N_NODES) return;

    int s = off[n];
    int e = off[n + 1];

    float acc[8];
    #pragma unroll
    for (int j = 0; j < 8; ++j) acc[j] = 0.0f;

    int i = s;
    // scalar prologue to 4-edge alignment
    for (; i < e && (i & 3); ++i) {
        unsigned p = epk[i];
        float v = __uint_as_float(p & 0xFFFF0000u);
        uint4 r = *(const uint4*)(support + (size_t)(p & 0xFFFFu) * D_FEAT + q * 8);
        const unsigned* u = (const unsigned*)&r;
        #pragma unroll
        for (int w2 = 0; w2 < 4; ++w2) {
            acc[w2*2+0] = fmaf(__uint_as_float(u[w2] << 16),         v, acc[w2*2+0]);
            acc[w2*2+1] = fmaf(__uint_as_float(u[w2] & 0xFFFF0000u), v, acc[w2*2+1]);
        }
    }
    // 4 edges per uint4
    for (; i + 4 <= e; i += 4) {
        uint4 pq = *(const uint4*)(epk + i);
        const unsigned* pp = (const unsigned*)&pq;
        uint4 r0 = *(const uint4*)(support + (size_t)(pp[0] & 0xFFFFu) * D_FEAT + q * 8);
        uint4 r1 = *(const uint4*)(support + (size_t)(pp[1] & 0xFFFFu) * D_FEAT + q * 8);
        uint4 r2 = *(const uint4*)(support + (size_t)(pp[2] & 0xFFFFu) * D_FEAT + q * 8);
        uint4 r3 = *(const uint4*)(support + (size_t)(pp[3] & 0xFFFFu) * D_FEAT + q * 8);
        float v0 = __uint_as_float(pp[0] & 0xFFFF0000u);
        float v1 = __uint_as_float(pp[1] & 0xFFFF0000u);
        float v2 = __uint_as_float(pp[2] & 0xFFFF0000u);
        float v3 = __uint_as_float(pp[3] & 0xFFFF0000u);
        const unsigned* u0 = (const unsigned*)&r0;
        const unsigned* u1 = (const unsigned*)&r1;
        const unsigned* u2 = (const unsigned*)&r2;
        const unsigned* u3 = (const unsigned*)&r3;
        #pragma unroll
        for (int w2 = 0; w2 < 4; ++w2) {
            acc[w2*2+0] = fmaf(__uint_as_float(u0[w2] << 16),         v0, acc[w2*2+0]);
            acc[w2*2+1] = fmaf(__uint_as_float(u0[w2] & 0xFFFF0000u), v0, acc[w2*2+1]);
            acc[w2*2+0] = fmaf(__uint_as_float(u1[w2] << 16),         v1, acc[w2*2+0]);
            acc[w2*2+1] = fmaf(__uint_as_float(u1[w2] & 0xFFFF0000u), v1, acc[w2*2+1]);
            acc[w2*2+0] = fmaf(__uint_as_float(u2[w2] << 16),         v2, acc[w2*2+0]);
            acc[w2*2+1] = fmaf(__uint_as_float(u2[w2] & 0xFFFF0000u), v2, acc[w2*2+1]);
            acc[w2*2+0] = fmaf(__uint_as_float(u3[w2] << 16),         v3, acc[w2*2+0]);
            acc[w2*2+1] = fmaf(__uint_as_float(u3[w2] & 0xFFFF0000u), v3, acc[w2*2+1]);
        }
    }
    // scalar tail
    for (; i < e; ++i) {
        unsigned p = epk[i];
        float v = __uint_as_float(p & 0xFFFF0000u);
        uint4 r = *(const uint4*)(support + (size_t)(p & 0xFFFFu) * D_FEAT + q * 8);
        const unsigned* u = (const unsigned*)&r;
        #pragma unroll
        for (int w2 = 0; w2 < 4; ++w2) {
            acc[w2*2+0] = fmaf(__uint_as_float(u[w2] << 16),         v, acc[w2*2+0]);
            acc[w2*2+1] = fmaf(__uint_as_float(u[w2] & 0xFFFF0000u), v, acc[w2*2+1]);
        }
    }

    const float* hrow = hin + (size_t)n * D_FEAT + q * 8;
    const float* brow = b + q * 8;
    float* orow = hout + (size_t)n * D_FEAT + q * 8;
    float og[8];
    #pragma unroll
    for (int g = 0; g < 2; ++g) {
        float4 hv = *(const float4*)(hrow + g * 4);
        float4 bv = *(const float4*)(brow + g * 4);
        float4 o;
        o.x = fmaxf(0.5f * hv.x + 0.5f * (acc[g*4+0] + bv.x), 0.0f);
        o.y = fmaxf(0.5f * hv.y + 0.5f * (acc[g*4+1] + bv.y), 0.0f);
        o.z = fmaxf(0.5f * hv.z + 0.5f * (acc[g*4+2] + bv.z), 0.0f);
        o.w = fmaxf(0.5f * hv.w + 0.5f * (acc[g*4+3] + bv.w), 0.0f);
        *(float4*)(orow + g * 4) = o;
        og[g*4+0] = o.x; og[g*4+1] = o.y; og[g*4+2] = o.z; og[g*4+3] = o.w;
    }
    uint4 pk; unsigned* pku = (unsigned*)&pk;
    #pragma unroll
    for (int w2 = 0; w2 < 4; ++w2) {
        unsigned lo = f2bf(og[w2 * 2 + 0]);
        unsigned hi = f2bf(og[w2 * 2 + 1]);
        pku[w2] = lo | (hi << 16);
    }
    *(uint4*)(hb + (size_t)n * D_FEAT + q * 8) = pk;
}

// ---------------------------------------------------------------------------
// Kernel 3: logits = h @ W_lin ; out = log_softmax(logits)  (f32)
// ---------------------------------------------------------------------------
__global__ __launch_bounds__(256) void k_final(const float* __restrict__ h,
                                               const float* __restrict__ Wg,
                                               float* __restrict__ out) {
    __shared__ float Wl[D_FEAT * C_CLS];
    {
        const float4* src = (const float4*)Wg;
        float4* dst = (float4*)Wl;
        for (int i = threadIdx.x; i < 960; i += 256) dst[i] = src[i];
    }
    __syncthreads();

    int n = blockIdx.x * 256 + threadIdx.x;
    if (n >= N_NODES) return;

    float acc[C_CLS];
    #pragma unroll
    for (int c = 0; c < C_CLS; ++c) acc[c] = 0.0f;

    const float4* hrow = (const float4*)(h + (size_t)n * D_FEAT);
    for (int k4 = 0; k4 < 24; ++k4) {
        float4 hv = hrow[k4];
        const float* hvf = (const float*)&hv;
        #pragma unroll
        for (int kk = 0; kk < 4; ++kk) {
            float hs = hvf[kk];
            const float* wr = &Wl[(k4 * 4 + kk) * C_CLS];
            #pragma unroll
            for (int c4 = 0; c4 < 10; ++c4) {
                float4 w = *(const float4*)(wr + c4 * 4);
                acc[c4 * 4 + 0] = fmaf(hs, w.x, acc[c4 * 4 + 0]);
                acc[c4 * 4 + 1] = fmaf(hs, w.y, acc[c4 * 4 + 1]);
                acc[c4 * 4 + 2] = fmaf(hs, w.z, acc[c4 * 4 + 2]);
                acc[c4 * 4 + 3] = fmaf(hs, w.w, acc[c4 * 4 + 3]);
            }
        }
    }

    float m = acc[0];
    #pragma unroll
    for (int c = 1; c < C_CLS; ++c) m = fmaxf(m, acc[c]);
    float s = 0.0f;
    #pragma unroll
    for (int c = 0; c < C_CLS; ++c) s += expf(acc[c] - m);
    float lse = m + logf(s);

    float* orow = out + (size_t)n * C_CLS;
    #pragma unroll
    for (int c4 = 0; c4 < 10; ++c4)
        *(float4*)(orow + c4 * 4) =
            make_float4(acc[c4 * 4 + 0] - lse, acc[c4 * 4 + 1] - lse,
                        acc[c4 * 4 + 2] - lse, acc[c4 * 4 + 3] - lse);
}

// ---------------------------------------------------------------------------
static inline size_t align256(size_t x) { return (x + 255) & ~(size_t)255; }

extern "C" void kernel_launch(void* const* d_in, const int* in_sizes, int n_in,
                              void* d_out, int out_size, void* d_ws, size_t ws_size,
                              hipStream_t stream) {
    const float* x    = (const float*)d_in[0];
    const int*   erow = (const int*)  d_in[1];
    const int*   ecol = (const int*)  d_in[2];
    const float* ev   = (const float*)d_in[3];
    const float* Wgc  = (const float*)d_in[4];
    const float* bgc  = (const float*)d_in[5];
    const float* Wlin = (const float*)d_in[6];
    float* out = (float*)d_out;

    const size_t NF = (size_t)N_NODES * D_FEAT;
    char* ws = (char*)d_ws;
    float*          h          = (float*)ws;          ws += align256(NF * 4);              // 19.2 MB
    unsigned short* support_bf = (unsigned short*)ws; ws += align256(NF * 2);              // 9.6 MB
    unsigned short* hb         = (unsigned short*)ws; ws += align256(NF * 2);              // 9.6 MB
    unsigned short* xb         = (unsigned short*)ws; ws += align256(NF * 2);              // 9.6 MB
    unsigned*       epk        = (unsigned*)ws;       ws += align256((size_t)E_EDGES * 4); // 3.2 MB
    unsigned short* WB         = (unsigned short*)ws; ws += align256((size_t)18 * 64 * 8 * 2);
    int*            off        = (int*)ws;            ws += align256((size_t)(N_NODES + 1) * 4);
    int*            deg        = (int*)ws;            ws += align256((size_t)N_NODES * 4);
    int*            cursor     = (int*)ws;            ws += align256((size_t)N_NODES * 4);
    int*            bsum       = (int*)ws;            ws += align256((size_t)SCAN_NB * 4);

    // ---- one-time prep + CSR build ----
    hipMemsetAsync(deg, 0, (size_t)N_NODES * 4, stream);
    k_prep_w     <<<1, 256, 0, stream>>>(Wgc, WB);
    k_cvt_bf16   <<<(int)((NF / 8 + 255) / 256), 256, 0, stream>>>(x, xb, (int)(NF / 8));
    k_hist       <<<(E_EDGES + 255) / 256, 256, 0, stream>>>(erow, deg);
    k_scan_reduce<<<SCAN_NB, 256, 0, stream>>>(deg, bsum);
    k_scan_tops  <<<1, 64, 0, stream>>>(bsum);
    k_scan_add   <<<SCAN_NB, 256, 0, stream>>>(deg, bsum, off, cursor);
    k_build      <<<(E_EDGES + 255) / 256, 256, 0, stream>>>(erow, ecol, ev, cursor, epk);

    // ---- 8 GCN iterations ----
    const int g_mm = (N_NODES + 63) / 64;
    const int g_ag = (N_NODES * 12 + 191) / 192;
    for (int it = 0; it < N_ITER; ++it) {
        const unsigned short* hin_bf = (it == 0) ? xb : hb;
        const float*          hin    = (it == 0) ? x  : h;
        k_matmul_mfma<<<g_mm, 256, 0, stream>>>(hin_bf, WB, support_bf);
        k_agg        <<<g_ag, 192, 0, stream>>>(off, epk, support_bf, hin, bgc, h, hb);
    }
    k_final<<<(N_NODES + 255) / 256, 256, 0, stream>>>(h, Wlin, out);
}

// Round 7
// 442.737 us; speedup vs baseline: 18.9060x; 1.1942x over previous
//
#include <hip/hip_runtime.h>

#define N_NODES 50000
#define E_EDGES 800000
#define D_FEAT  96
#define C_CLS   40
#define N_ITER  8

#define SCAN_CHUNK 1024
#define SCAN_NB ((N_NODES + SCAN_CHUNK - 1) / SCAN_CHUNK)   // 49

typedef short bf16x8 __attribute__((ext_vector_type(8)));   // 8 bf16 = 4 VGPRs
typedef float f32x4  __attribute__((ext_vector_type(4)));
typedef float f32x2  __attribute__((ext_vector_type(2)));

#if defined(__has_builtin)
#if __has_builtin(__builtin_amdgcn_cvt_pk_f32_fp8) && __has_builtin(__builtin_amdgcn_cvt_pk_fp8_f32)
#define HAVE_FP8_CVT 1
#endif
#endif
#ifndef HAVE_FP8_CVT
#define HAVE_FP8_CVT 0
#endif

// bf16 helpers (RNE)
static __device__ __forceinline__ unsigned short f2bf(float f) {
    unsigned u = __float_as_uint(f);
    u = (u + 0x7FFF + ((u >> 16) & 1)) >> 16;
    return (unsigned short)u;
}

// ---- fp8 e4m3fn manual fallback (normals only; encode flushes subnormals) ----
static __device__ __forceinline__ unsigned f32_to_fp8_manual(float f) {
    unsigned u = __float_as_uint(f);
    unsigned s = u >> 31;
    int e8 = (int)((u >> 23) & 0xFF) - 127 + 7;
    unsigned m23 = u & 0x7FFFFF;
    if (e8 <= 0) return s << 7;
    if (e8 >= 15) return (s << 7) | 0x7E;
    unsigned m = m23 >> 20;
    unsigned rem = m23 & 0xFFFFF;
    if (rem > 0x80000u || (rem == 0x80000u && (m & 1))) {
        m++;
        if (m == 8) { m = 0; e8++; if (e8 >= 15) return (s << 7) | 0x7E; }
    }
    return (s << 7) | ((unsigned)e8 << 3) | m;
}
static __device__ __forceinline__ float fp8_to_f32_manual(unsigned b) {
    unsigned s = (b >> 7) & 1, e = (b >> 3) & 0xF, m = b & 7;
    if (e == 0) return 0.0f;
    return __uint_as_float((s << 31) | ((e + 120) << 23) | (m << 20));
}

// decode 4 fp8 (one uint) -> 4 f32
static __device__ __forceinline__ void fp8x4_dec(unsigned w, float* o) {
#if HAVE_FP8_CVT
    f32x2 lo = __builtin_amdgcn_cvt_pk_f32_fp8(w, false);
    f32x2 hi = __builtin_amdgcn_cvt_pk_f32_fp8(w, true);
    o[0] = lo[0]; o[1] = lo[1]; o[2] = hi[0]; o[3] = hi[1];
#else
    o[0] = fp8_to_f32_manual(w & 0xFF);
    o[1] = fp8_to_f32_manual((w >> 8) & 0xFF);
    o[2] = fp8_to_f32_manual((w >> 16) & 0xFF);
    o[3] = fp8_to_f32_manual((w >> 24) & 0xFF);
#endif
}
// encode 4 f32 -> one uint of fp8
static __device__ __forceinline__ unsigned fp8x4_enc(float a, float b, float c, float d) {
#if HAVE_FP8_CVT
    unsigned w = __builtin_amdgcn_cvt_pk_fp8_f32(a, b, 0, false);
    w = __builtin_amdgcn_cvt_pk_fp8_f32(c, d, (int)w, true);
    return w;
#else
    return f32_to_fp8_manual(a) | (f32_to_fp8_manual(b) << 8) |
           (f32_to_fp8_manual(c) << 16) | (f32_to_fp8_manual(d) << 24);
#endif
}

// ---------------------------------------------------------------------------
// CSR build, step 1: degree histogram
// ---------------------------------------------------------------------------
__global__ __launch_bounds__(256) void k_hist(const int* __restrict__ erow,
                                              int* __restrict__ deg) {
    int e = blockIdx.x * 256 + threadIdx.x;
    if (e >= E_EDGES) return;
    atomicAdd(&deg[erow[e]], 1);
}

// ---------------------------------------------------------------------------
// CSR scan 1/3: per-chunk reduction
// ---------------------------------------------------------------------------
__global__ __launch_bounds__(256) void k_scan_reduce(const int* __restrict__ deg,
                                                     int* __restrict__ bsum) {
    __shared__ int sbuf[256];
    int tid = threadIdx.x;
    int base = blockIdx.x * SCAN_CHUNK + tid * 4;
    int s = 0;
    #pragma unroll
    for (int j = 0; j < 4; ++j) {
        int idx = base + j;
        if (idx < N_NODES) s += deg[idx];
    }
    sbuf[tid] = s;
    __syncthreads();
    for (int d = 128; d > 0; d >>= 1) {
        if (tid < d) sbuf[tid] += sbuf[tid + d];
        __syncthreads();
    }
    if (tid == 0) bsum[blockIdx.x] = sbuf[0];
}

// ---------------------------------------------------------------------------
// CSR scan 2/3: exclusive scan of 49 block sums, one wave
// ---------------------------------------------------------------------------
__global__ __launch_bounds__(64) void k_scan_tops(int* __restrict__ bsum) {
    int lane = threadIdx.x;
    int v = (lane < SCAN_NB) ? bsum[lane] : 0;
    int inc = v;
    #pragma unroll
    for (int d = 1; d < 64; d <<= 1) {
        int up = __shfl_up(inc, d, 64);
        if (lane >= d) inc += up;
    }
    if (lane < SCAN_NB) bsum[lane] = inc - v;
}

// ---------------------------------------------------------------------------
// CSR scan 3/3: block-local scan + offset
// ---------------------------------------------------------------------------
__global__ __launch_bounds__(256) void k_scan_add(const int* __restrict__ deg,
                                                  const int* __restrict__ bsum_ex,
                                                  int* __restrict__ off,
                                                  int* __restrict__ cursor) {
    __shared__ int sbuf[256];
    int tid = threadIdx.x;
    int base = blockIdx.x * SCAN_CHUNK + tid * 4;
    int v[4];
    int s = 0;
    #pragma unroll
    for (int j = 0; j < 4; ++j) {
        int idx = base + j;
        v[j] = (idx < N_NODES) ? deg[idx] : 0;
        s += v[j];
    }
    sbuf[tid] = s;
    __syncthreads();
    for (int d = 1; d < 256; d <<= 1) {
        int t = (tid >= d) ? sbuf[tid - d] : 0;
        __syncthreads();
        sbuf[tid] += t;
        __syncthreads();
    }
    int ex = bsum_ex[blockIdx.x] + sbuf[tid] - s;
    #pragma unroll
    for (int j = 0; j < 4; ++j) {
        int idx = base + j;
        if (idx < N_NODES) {
            off[idx] = ex;
            cursor[idx] = ex;
            ex += v[j];
        }
    }
    if (blockIdx.x == 0 && tid == 0) off[N_NODES] = E_EDGES;
}

// ---------------------------------------------------------------------------
// CSR build, step 3: bucket-scatter packed edges (4B: col | bf16(val)<<16)
// ---------------------------------------------------------------------------
__global__ __launch_bounds__(256) void k_build(const int* __restrict__ erow,
                                               const int* __restrict__ ecol,
                                               const float* __restrict__ eval_,
                                               int* __restrict__ cursor,
                                               unsigned* __restrict__ epk) {
    int e = blockIdx.x * 256 + threadIdx.x;
    if (e >= E_EDGES) return;
    int r = erow[e];
    int pos = atomicAdd(&cursor[r], 1);
    unsigned pk = (unsigned)(ecol[e] & 0xFFFF) | ((unsigned)f2bf(eval_[e]) << 16);
    epk[pos] = pk;
}

// ---------------------------------------------------------------------------
// One-time: repack W_gc into MFMA B-fragment order, bf16.
// ---------------------------------------------------------------------------
__global__ __launch_bounds__(256) void k_prep_w(const float* __restrict__ W,
                                                unsigned short* __restrict__ WB) {
    for (int idx = threadIdx.x; idx < 18 * 64; idx += 256) {
        int grp = idx >> 6;
        int lane = idx & 63;
        int t = grp / 3, s = grp - t * 3;
        int n = t * 16 + (lane & 15);
        int k0 = s * 32 + (lane >> 4) * 8;
        unsigned short* dst = WB + (size_t)idx * 8;
        #pragma unroll
        for (int j = 0; j < 8; ++j)
            dst[j] = f2bf(W[(k0 + j) * D_FEAT + n]);
    }
}

// ---------------------------------------------------------------------------
// One-time: f32 -> bf16 row conversion (x at iteration 0)
// ---------------------------------------------------------------------------
__global__ __launch_bounds__(256) void k_cvt_bf16(const float* __restrict__ src,
                                                  unsigned short* __restrict__ dst,
                                                  int n8) {
    int g = blockIdx.x * 256 + threadIdx.x;
    if (g >= n8) return;
    const float4* s4 = (const float4*)src + (size_t)g * 2;
    float4 x0 = s4[0], x1 = s4[1];
    float vals[8] = {x0.x, x0.y, x0.z, x0.w, x1.x, x1.y, x1.z, x1.w};
    uint4 pk; unsigned* pku = (unsigned*)&pk;
    #pragma unroll
    for (int w2 = 0; w2 < 4; ++w2) {
        unsigned lo = f2bf(vals[w2 * 2 + 0]);
        unsigned hi = f2bf(vals[w2 * 2 + 1]);
        pku[w2] = lo | (hi << 16);
    }
    *(uint4*)(dst + (size_t)g * 8) = pk;
}

// ---------------------------------------------------------------------------
// Kernel 1: support(fp8) = hb(bf16) @ WB(bf16) via MFMA 16x16x32, f32 acc,
// single HW conversion to fp8 e4m3 on store. Row = 96 B.
// ---------------------------------------------------------------------------
__global__ __launch_bounds__(256) void k_matmul_mfma(
        const unsigned short* __restrict__ hb,
        const unsigned short* __restrict__ WB,
        unsigned char* __restrict__ support) {
    __shared__ float sm[64 * 100];
    int tid = threadIdx.x;
    int wave = tid >> 6, lane = tid & 63;
    int q = lane >> 4, c = lane & 15;
    int m0 = blockIdx.x * 64 + wave * 16;

    if (m0 < N_NODES) {
        const unsigned short* arow = hb + (size_t)(m0 + c) * D_FEAT + q * 8;
        bf16x8 a0 = *(const bf16x8*)(arow);
        bf16x8 a1 = *(const bf16x8*)(arow + 32);
        bf16x8 a2 = *(const bf16x8*)(arow + 64);
        #pragma unroll
        for (int t = 0; t < 6; ++t) {
            const unsigned short* bp = WB + ((size_t)(t * 3) * 64 + lane) * 8;
            bf16x8 b0 = *(const bf16x8*)(bp);
            bf16x8 b1 = *(const bf16x8*)(bp + 64 * 8);
            bf16x8 b2 = *(const bf16x8*)(bp + 128 * 8);
            f32x4 acc = {0.f, 0.f, 0.f, 0.f};
            acc = __builtin_amdgcn_mfma_f32_16x16x32_bf16(a0, b0, acc, 0, 0, 0);
            acc = __builtin_amdgcn_mfma_f32_16x16x32_bf16(a1, b1, acc, 0, 0, 0);
            acc = __builtin_amdgcn_mfma_f32_16x16x32_bf16(a2, b2, acc, 0, 0, 0);
            #pragma unroll
            for (int r = 0; r < 4; ++r)
                sm[(wave * 16 + q * 4 + r) * 100 + t * 16 + c] = acc[r];
        }
    }
    __syncthreads();

    // readback: 64 rows x 12 chunks of 8 cols = 768 uint2 stores, 3/thread
    #pragma unroll
    for (int oo = 0; oo < 3; ++oo) {
        int o = tid + oo * 256;
        int row = o / 12;
        int cb = (o - row * 12) * 8;
        int grow = blockIdx.x * 64 + row;
        if (grow < N_NODES) {
            const float* sp = sm + row * 100 + cb;
            uint2 pk;
            pk.x = fp8x4_enc(sp[0], sp[1], sp[2], sp[3]);
            pk.y = fp8x4_enc(sp[4], sp[5], sp[6], sp[7]);
            *(uint2*)(support + (size_t)grow * D_FEAT + cb) = pk;
        }
    }
}

// ---------------------------------------------------------------------------
// Kernel 2 (fused agg+combine): 12 threads/node, 8 fp8 cols (8B load) each.
// State is bf16-only (hb), updated in place (own-slice read precedes write).
//   agg = sum_e fp8dec(support[col(e)]) * val(e)
//   hb[n] = bf16(relu(0.5*bf16dec(hin[n]) + 0.5*(agg + b)))
// ---------------------------------------------------------------------------
__global__ __launch_bounds__(192) void k_agg(const int* __restrict__ off,
                                             const unsigned* __restrict__ epk,
                                             const unsigned char* __restrict__ support,
                                             const unsigned short* hin,
                                             const float* __restrict__ b,
                                             unsigned short* hout) {
    int gid = blockIdx.x * 192 + threadIdx.x;
    int n = gid / 12;
    int q = gid % 12;
    if (n >= N_NODES) return;

    int s = off[n];
    int e = off[n + 1];

    float acc[8];
    #pragma unroll
    for (int j = 0; j < 8; ++j) acc[j] = 0.0f;

    int i = s;
    for (; i < e && (i & 3); ++i) {
        unsigned p = epk[i];
        float v = __uint_as_float(p & 0xFFFF0000u);
        uint2 r = *(const uint2*)(support + (size_t)(p & 0xFFFFu) * D_FEAT + q * 8);
        float f[8];
        fp8x4_dec(r.x, f);
        fp8x4_dec(r.y, f + 4);
        #pragma unroll
        for (int j = 0; j < 8; ++j) acc[j] = fmaf(f[j], v, acc[j]);
    }
    for (; i + 4 <= e; i += 4) {
        uint4 pq = *(const uint4*)(epk + i);
        const unsigned* pp = (const unsigned*)&pq;
        uint2 r0 = *(const uint2*)(support + (size_t)(pp[0] & 0xFFFFu) * D_FEAT + q * 8);
        uint2 r1 = *(const uint2*)(support + (size_t)(pp[1] & 0xFFFFu) * D_FEAT + q * 8);
        uint2 r2 = *(const uint2*)(support + (size_t)(pp[2] & 0xFFFFu) * D_FEAT + q * 8);
        uint2 r3 = *(const uint2*)(support + (size_t)(pp[3] & 0xFFFFu) * D_FEAT + q * 8);
        float v0 = __uint_as_float(pp[0] & 0xFFFF0000u);
        float v1 = __uint_as_float(pp[1] & 0xFFFF0000u);
        float v2 = __uint_as_float(pp[2] & 0xFFFF0000u);
        float v3 = __uint_as_float(pp[3] & 0xFFFF0000u);
        float f0[8], f1[8], f2[8], f3[8];
        fp8x4_dec(r0.x, f0); fp8x4_dec(r0.y, f0 + 4);
        fp8x4_dec(r1.x, f1); fp8x4_dec(r1.y, f1 + 4);
        fp8x4_dec(r2.x, f2); fp8x4_dec(r2.y, f2 + 4);
        fp8x4_dec(r3.x, f3); fp8x4_dec(r3.y, f3 + 4);
        #pragma unroll
        for (int j = 0; j < 8; ++j) {
            acc[j] = fmaf(f0[j], v0, acc[j]);
            acc[j] = fmaf(f1[j], v1, acc[j]);
            acc[j] = fmaf(f2[j], v2, acc[j]);
            acc[j] = fmaf(f3[j], v3, acc[j]);
        }
    }
    for (; i < e; ++i) {
        unsigned p = epk[i];
        float v = __uint_as_float(p & 0xFFFF0000u);
        uint2 r = *(const uint2*)(support + (size_t)(p & 0xFFFFu) * D_FEAT + q * 8);
        float f[8];
        fp8x4_dec(r.x, f);
        fp8x4_dec(r.y, f + 4);
        #pragma unroll
        for (int j = 0; j < 8; ++j) acc[j] = fmaf(f[j], v, acc[j]);
    }

    // skip + bias + relu, bf16 state in/out
    uint4 hq = *(const uint4*)(hin + (size_t)n * D_FEAT + q * 8);
    const unsigned* hu = (const unsigned*)&hq;
    const float* brow = b + q * 8;
    float og[8];
    #pragma unroll
    for (int w2 = 0; w2 < 4; ++w2) {
        float h0 = __uint_as_float(hu[w2] << 16);
        float h1 = __uint_as_float(hu[w2] & 0xFFFF0000u);
        og[w2*2+0] = fmaxf(0.5f * h0 + 0.5f * (acc[w2*2+0] + brow[w2*2+0]), 0.0f);
        og[w2*2+1] = fmaxf(0.5f * h1 + 0.5f * (acc[w2*2+1] + brow[w2*2+1]), 0.0f);
    }
    uint4 pk; unsigned* pku = (unsigned*)&pk;
    #pragma unroll
    for (int w2 = 0; w2 < 4; ++w2) {
        unsigned lo = f2bf(og[w2 * 2 + 0]);
        unsigned hi = f2bf(og[w2 * 2 + 1]);
        pku[w2] = lo | (hi << 16);
    }
    *(uint4*)(hout + (size_t)n * D_FEAT + q * 8) = pk;
}

// ---------------------------------------------------------------------------
// Kernel 3: logits = bf16dec(hb) @ W_lin ; out = log_softmax (f32 math)
// ---------------------------------------------------------------------------
__global__ __launch_bounds__(256) void k_final(const unsigned short* __restrict__ hb,
                                               const float* __restrict__ Wg,
                                               float* __restrict__ out) {
    __shared__ float Wl[D_FEAT * C_CLS];
    {
        const float4* src = (const float4*)Wg;
        float4* dst = (float4*)Wl;
        for (int i = threadIdx.x; i < 960; i += 256) dst[i] = src[i];
    }
    __syncthreads();

    int n = blockIdx.x * 256 + threadIdx.x;
    if (n >= N_NODES) return;

    float acc[C_CLS];
    #pragma unroll
    for (int c = 0; c < C_CLS; ++c) acc[c] = 0.0f;

    const unsigned short* hrow = hb + (size_t)n * D_FEAT;
    for (int g = 0; g < 12; ++g) {
        uint4 hq = *(const uint4*)(hrow + g * 8);
        const unsigned* hu = (const unsigned*)&hq;
        float hv[8];
        #pragma unroll
        for (int w2 = 0; w2 < 4; ++w2) {
            hv[w2*2+0] = __uint_as_float(hu[w2] << 16);
            hv[w2*2+1] = __uint_as_float(hu[w2] & 0xFFFF0000u);
        }
        #pragma unroll
        for (int kk = 0; kk < 8; ++kk) {
            float hs = hv[kk];
            const float* wr = &Wl[(g * 8 + kk) * C_CLS];
            #pragma unroll
            for (int c4 = 0; c4 < 10; ++c4) {
                float4 w = *(const float4*)(wr + c4 * 4);
                acc[c4 * 4 + 0] = fmaf(hs, w.x, acc[c4 * 4 + 0]);
                acc[c4 * 4 + 1] = fmaf(hs, w.y, acc[c4 * 4 + 1]);
                acc[c4 * 4 + 2] = fmaf(hs, w.z, acc[c4 * 4 + 2]);
                acc[c4 * 4 + 3] = fmaf(hs, w.w, acc[c4 * 4 + 3]);
            }
        }
    }

    float m = acc[0];
    #pragma unroll
    for (int c = 1; c < C_CLS; ++c) m = fmaxf(m, acc[c]);
    float s = 0.0f;
    #pragma unroll
    for (int c = 0; c < C_CLS; ++c) s += expf(acc[c] - m);
    float lse = m + logf(s);

    float* orow = out + (size_t)n * C_CLS;
    #pragma unroll
    for (int c4 = 0; c4 < 10; ++c4)
        *(float4*)(orow + c4 * 4) =
            make_float4(acc[c4 * 4 + 0] - lse, acc[c4 * 4 + 1] - lse,
                        acc[c4 * 4 + 2] - lse, acc[c4 * 4 + 3] - lse);
}

// ---------------------------------------------------------------------------
static inline size_t align256(size_t x) { return (x + 255) & ~(size_t)255; }

extern "C" void kernel_launch(void* const* d_in, const int* in_sizes, int n_in,
                              void* d_out, int out_size, void* d_ws, size_t ws_size,
                              hipStream_t stream) {
    const float* x    = (const float*)d_in[0];
    const int*   erow = (const int*)  d_in[1];
    const int*   ecol = (const int*)  d_in[2];
    const float* ev   = (const float*)d_in[3];
    const float* Wgc  = (const float*)d_in[4];
    const float* bgc  = (const float*)d_in[5];
    const float* Wlin = (const float*)d_in[6];
    float* out = (float*)d_out;

    const size_t NF = (size_t)N_NODES * D_FEAT;
    char* ws = (char*)d_ws;
    unsigned short* hb         = (unsigned short*)ws; ws += align256(NF * 2);              // 9.6 MB
    unsigned short* xb         = (unsigned short*)ws; ws += align256(NF * 2);              // 9.6 MB
    unsigned char*  support_f8 = (unsigned char*)ws;  ws += align256(NF);                  // 4.8 MB
    unsigned*       epk        = (unsigned*)ws;       ws += align256((size_t)E_EDGES * 4); // 3.2 MB
    unsigned short* WB         = (unsigned short*)ws; ws += align256((size_t)18 * 64 * 8 * 2);
    int*            off        = (int*)ws;            ws += align256((size_t)(N_NODES + 1) * 4);
    int*            deg        = (int*)ws;            ws += align256((size_t)N_NODES * 4);
    int*            cursor     = (int*)ws;            ws += align256((size_t)N_NODES * 4);
    int*            bsum       = (int*)ws;            ws += align256((size_t)SCAN_NB * 4);

    // ---- one-time prep + CSR build ----
    hipMemsetAsync(deg, 0, (size_t)N_NODES * 4, stream);
    k_prep_w     <<<1, 256, 0, stream>>>(Wgc, WB);
    k_cvt_bf16   <<<(int)((NF / 8 + 255) / 256), 256, 0, stream>>>(x, xb, (int)(NF / 8));
    k_hist       <<<(E_EDGES + 255) / 256, 256, 0, stream>>>(erow, deg);
    k_scan_reduce<<<SCAN_NB, 256, 0, stream>>>(deg, bsum);
    k_scan_tops  <<<1, 64, 0, stream>>>(bsum);
    k_scan_add   <<<SCAN_NB, 256, 0, stream>>>(deg, bsum, off, cursor);
    k_build      <<<(E_EDGES + 255) / 256, 256, 0, stream>>>(erow, ecol, ev, cursor, epk);

    // ---- 8 GCN iterations (bf16 state hb, in-place) ----
    const int g_mm = (N_NODES + 63) / 64;
    const int g_ag = (N_NODES * 12 + 191) / 192;
    for (int it = 0; it < N_ITER; ++it) {
        const unsigned short* hin = (it == 0) ? xb : hb;
        k_matmul_mfma<<<g_mm, 256, 0, stream>>>(hin, WB, support_f8);
        k_agg        <<<g_ag, 192, 0, stream>>>(off, epk, support_f8, hin, bgc, hb);
    }
    k_final<<<(N_NODES + 255) / 256, 256, 0, stream>>>(hb, Wlin, out);
}